// Round 7
// baseline (2054.005 us; speedup 1.0000x reference)
//
#include <hip/hip_runtime.h>

#define N_NODES 81920
#define N_EDGES 1310720
#define NG 256
#define D 64
#define TM 64
#define SA 65            // LDS row stride: 2-way bank alias max (free)
#define NB 320           // 256-thread node blocks covering N_NODES
#define NBLK 1280        // src blocks of 64 nodes
#define BMW 2560         // bitmask words (81920/32)
#define RPW 1296         // padded row_ptr stride (>= NBLK+1)
#define HCHUNK 32768     // edges per histogram/bucket workgroup (40 WGs)

__device__ __forceinline__ bool tb(const unsigned* bm, int i) {
    return (bm[i >> 5] >> (i & 31)) & 1u;
}

// ---------------- tiny utility kernels ----------------

__global__ void zero_ints(int* __restrict__ p, int n) {
    int i = blockIdx.x * blockDim.x + threadIdx.x;
    if (i < n) p[i] = 0;
}

__global__ void zero_f4(float4* __restrict__ p, int n4) {
    int i = blockIdx.x * blockDim.x + threadIdx.x;
    if (i < n4) p[i] = make_float4(0.f, 0.f, 0.f, 0.f);
}

__global__ void find_first(const int* __restrict__ batch, int* __restrict__ fidx) {
    int i = blockIdx.x * blockDim.x + threadIdx.x;
    if (i < N_NODES) {
        int b = batch[i];
        if (i == 0 || batch[i - 1] != b) fidx[b] = i;
    }
}

__global__ void mark_set_bm(const int* __restrict__ fidx, unsigned* __restrict__ bm2,
                            unsigned* __restrict__ bm1) {
    int n = fidx[threadIdx.x];            // 1 block x 256
    atomicOr(&bm2[n >> 5], 1u << (n & 31));
    atomicOr(&bm1[n >> 5], 1u << (n & 31));
}

// mark srcs of edges with dst-bit set in bmD into bmS; optionally OR-copy orsrc into bmS
__global__ void mark_srcs_bm(const int* __restrict__ src, const int* __restrict__ dst,
                             const unsigned* __restrict__ bmD, unsigned* __restrict__ bmS,
                             const unsigned* __restrict__ orsrc) {
    if (orsrc && blockIdx.x == 0) {
        for (int w = threadIdx.x; w < BMW; w += 256)
            if (orsrc[w]) atomicOr(&bmS[w], orsrc[w]);
    }
    int e = blockIdx.x * 256 + threadIdx.x;
    if (e < N_EDGES && tb(bmD, dst[e])) {
        int s = src[e];
        atomicOr(&bmS[s >> 5], 1u << (s & 31));
    }
}

// compact two bitmasks -> node lists (order irrelevant)
__global__ void compact2_bm(const unsigned* __restrict__ bm0, const unsigned* __restrict__ bm1,
                            int* __restrict__ list0, int* __restrict__ list1,
                            int* __restrict__ n0, int* __restrict__ n1) {
    int i = blockIdx.x * 256 + threadIdx.x;
    int lane = threadIdx.x & 63;
    bool p0 = tb(bm0, i);
    bool p1 = tb(bm1, i);
    unsigned long long b0 = __ballot(p0);
    int lt = __popcll(b0 & ((1ull << lane) - 1));
    int base = 0;
    if (lane == 0 && b0) base = atomicAdd(n0, __popcll(b0));
    base = __shfl(base, 0);
    if (p0) list0[base + lt] = i;
    unsigned long long b1 = __ballot(p1);
    lt = __popcll(b1 & ((1ull << lane) - 1));
    base = 0;
    if (lane == 0 && b1) base = atomicAdd(n1, __popcll(b1));
    base = __shfl(base, 0);
    if (p1) list1[base + lt] = i;
}

// full in-degree, no global atomics: each WG owns a 2048-node range, scans all dsts
__global__ __launch_bounds__(256) void hist_indeg(const int* __restrict__ dst,
                                                  int* __restrict__ indeg) {
    __shared__ int h[2048];
    const int lo = blockIdx.x * 2048;     // 40 WGs
    for (int i = threadIdx.x; i < 2048; i += 256) h[i] = 0;
    __syncthreads();
    for (int e = threadIdx.x; e < N_EDGES; e += 256) {
        int r = dst[e] - lo;
        if ((unsigned)r < 2048u) atomicAdd(&h[r], 1);   // LDS atomic
    }
    __syncthreads();
    for (int i = threadIdx.x; i < 2048; i += 256) indeg[lo + i] = h[i];
}

// per-src-block counts for the three layers (LDS histograms + sparse merge)
__global__ __launch_bounds__(256) void hist_cnt(const int* __restrict__ src,
                                                const int* __restrict__ dst,
                                                const unsigned* __restrict__ bm0,
                                                const unsigned* __restrict__ bm1,
                                                const unsigned* __restrict__ bm2,
                                                int* __restrict__ cnt3b) {
    __shared__ int h0[NBLK], h1[NBLK], h2[NBLK];
    const int e0 = blockIdx.x * HCHUNK;   // 40 WGs
    for (int i = threadIdx.x; i < NBLK; i += 256) { h0[i] = 0; h1[i] = 0; h2[i] = 0; }
    __syncthreads();
    for (int e = e0 + threadIdx.x; e < e0 + HCHUNK; e += 256) {
        int d = dst[e];
        if (tb(bm0, d)) {
            int sb = src[e] >> 6;
            atomicAdd(&h0[sb], 1);
            if (tb(bm1, d)) {
                atomicAdd(&h1[sb], 1);
                if (tb(bm2, d)) atomicAdd(&h2[sb], 1);
            }
        }
    }
    __syncthreads();
    for (int i = threadIdx.x; i < NBLK; i += 256) {
        if (h0[i]) atomicAdd(&cnt3b[i], h0[i]);
        if (h1[i]) atomicAdd(&cnt3b[NBLK + i], h1[i]);
        if (h2[i]) atomicAdd(&cnt3b[2 * NBLK + i], h2[i]);
    }
}

// exclusive scan of 1280 counts x3 -> row_ptr + cursor init
__global__ void scan1280(const int* __restrict__ cnt3b, int* __restrict__ rp3b,
                         int* __restrict__ cur3b) {
    const int a = blockIdx.x;             // 3 blocks
    const int* c = cnt3b + a * NBLK;
    int* rp = rp3b + a * RPW;
    int* cu = cur3b + a * RPW;
    __shared__ int s[256];
    __shared__ int carry;
    int tid = threadIdx.x;
    if (tid == 0) carry = 0;
    __syncthreads();
    for (int r = 0; r < NBLK / 256; ++r) {
        int i = r * 256 + tid;
        int v = c[i];
        s[tid] = v;
        __syncthreads();
        for (int ofs = 1; ofs < 256; ofs <<= 1) {
            int t = (tid >= ofs) ? s[tid - ofs] : 0;
            __syncthreads();
            s[tid] += t;
            __syncthreads();
        }
        int excl = s[tid] - v + carry;
        rp[i] = excl;
        cu[i] = excl;
        __syncthreads();
        if (tid == 255) carry += s[255];
        __syncthreads();
    }
    if (tid == 0) rp[NBLK] = carry;
}

// bucket all three layers: per-WG LDS histogram -> bulk chunk reservation -> place
__global__ __launch_bounds__(256) void bucket3(const int* __restrict__ src,
                                               const int* __restrict__ dst,
                                               const unsigned* __restrict__ bm0,
                                               const unsigned* __restrict__ bm1,
                                               const unsigned* __restrict__ bm2,
                                               int* __restrict__ cur3b,
                                               int* __restrict__ esp0,
                                               int* __restrict__ esp1,
                                               int* __restrict__ esp2) {
    __shared__ int h0[NBLK], h1[NBLK], h2[NBLK];
    const int e0 = blockIdx.x * HCHUNK;   // 40 WGs
    for (int i = threadIdx.x; i < NBLK; i += 256) { h0[i] = 0; h1[i] = 0; h2[i] = 0; }
    __syncthreads();
    for (int e = e0 + threadIdx.x; e < e0 + HCHUNK; e += 256) {
        int d = dst[e];
        if (tb(bm0, d)) {
            int sb = src[e] >> 6;
            atomicAdd(&h0[sb], 1);
            if (tb(bm1, d)) {
                atomicAdd(&h1[sb], 1);
                if (tb(bm2, d)) atomicAdd(&h2[sb], 1);
            }
        }
    }
    __syncthreads();
    for (int i = threadIdx.x; i < NBLK; i += 256) {   // bulk-reserve chunks
        int c = h0[i]; h0[i] = c ? atomicAdd(&cur3b[i], c) : 0;
        c = h1[i];     h1[i] = c ? atomicAdd(&cur3b[RPW + i], c) : 0;
        c = h2[i];     h2[i] = c ? atomicAdd(&cur3b[2 * RPW + i], c) : 0;
    }
    __syncthreads();
    for (int e = e0 + threadIdx.x; e < e0 + HCHUNK; e += 256) {
        int d = dst[e];
        if (tb(bm0, d)) {
            int s = src[e];
            int sb = s >> 6;
            int pk = (d << 6) | (s & 63);
            int pos = atomicAdd(&h0[sb], 1);          // LDS cursor
            esp0[pos] = pk;
            if (tb(bm1, d)) {
                pos = atomicAdd(&h1[sb], 1);
                esp1[pos] = pk;
                if (tb(bm2, d)) {
                    pos = atomicAdd(&h2[sb], 1);
                    esp2[pos] = pk;
                }
            }
        }
    }
}

// ---------------- push phase: LDS-staged rows + fire-and-forget scatter atomics ----

__global__ __launch_bounds__(256, 8) void sage_push(
    const float* __restrict__ hin, const int* __restrict__ row_ptr,
    const int* __restrict__ esp, float* __restrict__ agg)
{
    __shared__ float Rs[TM * SA];     // this block's 64 src rows

    const int tid  = threadIdx.x;
    const int base = blockIdx.x * TM;
    const int lane = tid & 63;
    const int w    = tid >> 6;

    const int e0 = row_ptr[blockIdx.x];
    const int e1 = row_ptr[blockIdx.x + 1];
    if (e0 == e1) return;             // nothing to push from this block

    for (int idx = tid; idx < TM * D; idx += 256) {
        int m = idx >> 6, k = idx & 63;
        Rs[m * SA + k] = hin[(base << 6) + idx];   // coalesced stream
    }
    __syncthreads();

    const int chunk = ((e1 - e0) + 3) >> 2;
    int e = e0 + w * chunk;
    const int ee = min(e + chunk, e1);

    for (; e + 64 <= ee; e += 64) {
        int pv = esp[e + lane];                    // 64 edges, one coalesced load
        #pragma unroll
        for (int u = 0; u < 64; ++u) {
            int p = __shfl(pv, u);                 // broadcast edge u
            float v = Rs[(p & 63) * SA + lane];    // LDS row read, 2-way alias
            atomicAdd(&agg[(p & 0x7fffffc0) + lane], v);  // fire-and-forget f32 atomic
        }
    }
    for (; e < ee; ++e) {
        int p = esp[e];
        atomicAdd(&agg[(p & 0x7fffffc0) + lane], Rs[(p & 63) * SA + lane]);
    }
}

// ---------------- finish on a compacted node list: scale + dual fp32 GEMM + re-zero ----

__global__ __launch_bounds__(256, 4) void sage_finish_sel(
    const float* __restrict__ hin, float* __restrict__ agg,
    const int* __restrict__ indeg, const int* __restrict__ list,
    const int* __restrict__ pcount, float* __restrict__ hout,
    const float* __restrict__ Wl, const float* __restrict__ bl,
    const float* __restrict__ Wr, int relu)
{
    __shared__ float As[TM * SA];
    __shared__ float Xs[TM * SA];
    __shared__ float invs[TM];
    __shared__ int   nid[TM];

    const int cntv = *pcount;
    const int base = blockIdx.x * TM;
    if (base >= cntv) return;

    const int tid = threadIdx.x;
    if (tid < TM) {
        int n = (base + tid < cntv) ? list[base + tid] : -1;
        nid[tid]  = n;
        invs[tid] = (n >= 0) ? 1.0f / (float)max(indeg[n], 1) : 0.f;
    }
    __syncthreads();
    for (int idx = tid; idx < TM * D; idx += 256) {
        int m = idx >> 6, k = idx & 63;
        int n = nid[m];
        if (n >= 0) {
            As[m * SA + k] = agg[n * D + k] * invs[m];
            Xs[m * SA + k] = hin[n * D + k];
            agg[n * D + k] = 0.0f;                 // re-zero for the next push phase
        } else {
            As[m * SA + k] = 0.f;
            Xs[m * SA + k] = 0.f;
        }
    }
    __syncthreads();

    const int j0 = (tid & 15) << 2;
    const int m0 = (tid >> 4) << 2;
    float o[4][4];
    float4 b4 = *(const float4*)&bl[j0];
    #pragma unroll
    for (int mi = 0; mi < 4; ++mi) {
        o[mi][0] = b4.x; o[mi][1] = b4.y; o[mi][2] = b4.z; o[mi][3] = b4.w;
    }
    #pragma unroll 8
    for (int k = 0; k < D; ++k) {
        float4 wl = *(const float4*)&Wl[(k << 6) + j0];   // global, L1-resident broadcast
        float4 wr = *(const float4*)&Wr[(k << 6) + j0];
        #pragma unroll
        for (int mi = 0; mi < 4; ++mi) {
            float a = As[(m0 + mi) * SA + k];
            float x = Xs[(m0 + mi) * SA + k];
            o[mi][0] += a * wl.x + x * wr.x;
            o[mi][1] += a * wl.y + x * wr.y;
            o[mi][2] += a * wl.z + x * wr.z;
            o[mi][3] += a * wl.w + x * wr.w;
        }
    }
    #pragma unroll
    for (int mi = 0; mi < 4; ++mi) {
        int n = nid[m0 + mi];
        if (n >= 0) {
            float4 r = make_float4(o[mi][0], o[mi][1], o[mi][2], o[mi][3]);
            if (relu) {
                r.x = fmaxf(r.x, 0.f); r.y = fmaxf(r.y, 0.f);
                r.z = fmaxf(r.z, 0.f); r.w = fmaxf(r.w, 0.f);
            }
            *(float4*)&hout[n * D + j0] = r;
        }
    }
}

// ---------------- final layer GEMM on the 256 selected nodes ----------------

__global__ __launch_bounds__(256, 3) void final_gemm_sel(
    const float* __restrict__ hin, const float* __restrict__ agg,
    const int* __restrict__ indeg, const int* __restrict__ fidx,
    const float* __restrict__ Wl, const float* __restrict__ bl,
    const float* __restrict__ Wr, float* __restrict__ out)
{
    __shared__ float As[TM * SA];
    __shared__ float Xs[TM * SA];
    __shared__ int   nid[TM];
    __shared__ float invs[TM];

    const int tid  = threadIdx.x;
    const int base = blockIdx.x * TM;

    if (tid < TM) {
        int n = fidx[base + tid];
        nid[tid]  = n;
        invs[tid] = 1.0f / (float)max(indeg[n], 1);
    }
    __syncthreads();
    for (int idx = tid; idx < TM * D; idx += 256) {
        int m = idx >> 6, k = idx & 63;
        int n = nid[m];
        As[m * SA + k] = agg[n * D + k] * invs[m];
        Xs[m * SA + k] = hin[n * D + k];
    }
    __syncthreads();

    const int j0 = (tid & 15) << 2;
    const int m0 = (tid >> 4) << 2;
    float o[4][4];
    float4 b4 = *(const float4*)&bl[j0];
    #pragma unroll
    for (int mi = 0; mi < 4; ++mi) {
        o[mi][0] = b4.x; o[mi][1] = b4.y; o[mi][2] = b4.z; o[mi][3] = b4.w;
    }
    #pragma unroll 8
    for (int k = 0; k < D; ++k) {
        float4 wl = *(const float4*)&Wl[(k << 6) + j0];
        float4 wr = *(const float4*)&Wr[(k << 6) + j0];
        #pragma unroll
        for (int mi = 0; mi < 4; ++mi) {
            float a = As[(m0 + mi) * SA + k];
            float x = Xs[(m0 + mi) * SA + k];
            o[mi][0] += a * wl.x + x * wr.x;
            o[mi][1] += a * wl.y + x * wr.y;
            o[mi][2] += a * wl.z + x * wr.z;
            o[mi][3] += a * wl.w + x * wr.w;
        }
    }
    #pragma unroll
    for (int mi = 0; mi < 4; ++mi) {
        float4 r = make_float4(o[mi][0], o[mi][1], o[mi][2], o[mi][3]);
        *(float4*)&out[(base + m0 + mi) * D + j0] = r;
    }
}

// ---------------- launch ----------------

extern "C" void kernel_launch(void* const* d_in, const int* in_sizes, int n_in,
                              void* d_out, int out_size, void* d_ws, size_t ws_size,
                              hipStream_t stream)
{
    const float* x     = (const float*)d_in[0];
    const int*   ei    = (const int*)d_in[1];
    const int*   batch = (const int*)d_in[2];
    const float* Wl0 = (const float*)d_in[3];
    const float* bl0 = (const float*)d_in[4];
    const float* Wr0 = (const float*)d_in[5];
    const float* Wl1 = (const float*)d_in[6];
    const float* bl1 = (const float*)d_in[7];
    const float* Wr1 = (const float*)d_in[8];
    const float* Wl2 = (const float*)d_in[9];
    const float* bl2 = (const float*)d_in[10];
    const float* Wr2 = (const float*)d_in[11];
    float* out = (float*)d_out;

    const int* src = ei;             // edge_index[0]
    const int* dst = ei + N_EDGES;   // edge_index[1]

    char* ws = (char*)d_ws;
    size_t off = 0;
    auto alloc = [&](size_t bytes) -> void* {
        void* p = ws + off;
        off = (off + bytes + 255) & ~(size_t)255;
        return p;
    };
    int*   rp3b    = (int*)alloc((size_t)3 * RPW * sizeof(int));
    int*   cur3b   = (int*)alloc((size_t)3 * RPW * sizeof(int));
    int*   fidx    = (int*)alloc(NG * sizeof(int));
    int*   indeg   = (int*)alloc(N_NODES * sizeof(int));
    int*   list0   = (int*)alloc(N_NODES * sizeof(int));
    int*   list1   = (int*)alloc(N_NODES * sizeof(int));
    int*   esp0    = (int*)alloc((size_t)N_EDGES * sizeof(int));
    int*   esp1    = (int*)alloc((size_t)(N_EDGES / 4) * sizeof(int));   // ~69K expected
    int*   esp2    = (int*)alloc((size_t)(N_EDGES / 16) * sizeof(int));  // ~4K expected
    float* agg     = (float*)alloc((size_t)N_NODES * D * sizeof(float));
    float* h1      = (float*)alloc((size_t)N_NODES * D * sizeof(float));
    float* h2      = (float*)alloc((size_t)N_NODES * D * sizeof(float));
    // zeroable: bm0|bm1|bm2 (2560 words each), cnt3b (3*1280), n0, n1
    int*   zbase   = (int*)alloc((size_t)(3 * BMW + 3 * NBLK + 64) * sizeof(int));
    unsigned* bm0  = (unsigned*)zbase;
    unsigned* bm1  = (unsigned*)(zbase + BMW);
    unsigned* bm2  = (unsigned*)(zbase + 2 * BMW);
    int* cnt3b = zbase + 3 * BMW;
    int* n0    = zbase + 3 * BMW + 3 * NBLK;
    int* n1    = n0 + 1;
    (void)ws_size; (void)in_sizes; (void)n_in; (void)out_size;

    const int EB = (N_EDGES + 255) / 256;   // 5120
    const int ZN = 3 * BMW + 3 * NBLK + 64;

    zero_f4   <<<(N_NODES * D / 4 + 255) / 256, 256, 0, stream>>>((float4*)agg, N_NODES * D / 4);
    zero_ints <<<(ZN + 255) / 256, 256, 0, stream>>>(zbase, ZN);
    find_first<<<NB, 256, 0, stream>>>(batch, fidx);

    // masks (bitmasks): bm2 = outputs; bm1 = bm2 ∪ src(dst∈bm2); bm0 = bm1 ∪ src(dst∈bm1)
    mark_set_bm <<<1, NG, 0, stream>>>(fidx, bm2, bm1);
    mark_srcs_bm<<<EB, 256, 0, stream>>>(src, dst, bm2, bm1, (const unsigned*)nullptr);
    mark_srcs_bm<<<EB, 256, 0, stream>>>(src, dst, bm1, bm0, bm1);   // incl. OR-copy bm1->bm0
    compact2_bm <<<NB, 256, 0, stream>>>(bm0, bm1, list0, list1, n0, n1);

    // degree + CSR build (no random global atomics)
    hist_indeg<<<40, 256, 0, stream>>>(dst, indeg);
    hist_cnt  <<<40, 256, 0, stream>>>(src, dst, bm0, bm1, bm2, cnt3b);
    scan1280  <<<3, 256, 0, stream>>>(cnt3b, rp3b, cur3b);
    bucket3   <<<40, 256, 0, stream>>>(src, dst, bm0, bm1, bm2, cur3b, esp0, esp1, esp2);

    // layer 0: push dst∈m0, finish on m0 list
    sage_push      <<<NBLK, 256, 0, stream>>>(x, rp3b, esp0, agg);
    sage_finish_sel<<<NBLK, 256, 0, stream>>>(x, agg, indeg, list0, n0,
                                              h1, Wl0, bl0, Wr0, 1);
    // layer 1: push dst∈m1, finish on m1 list
    sage_push      <<<NBLK, 256, 0, stream>>>(h1, rp3b + RPW, esp1, agg);
    sage_finish_sel<<<NBLK, 256, 0, stream>>>(h1, agg, indeg, list1, n1,
                                              h2, Wl1, bl1, Wr1, 1);
    // layer 2: push dst∈m2, GEMM on the 256 output nodes
    sage_push      <<<NBLK, 256, 0, stream>>>(h2, rp3b + 2 * RPW, esp2, agg);
    final_gemm_sel <<<NG / TM, 256, 0, stream>>>(h2, agg, indeg, fidx, Wl2, bl2, Wr2, out);
}

// Round 8
// 745.129 us; speedup vs baseline: 2.7566x; 2.7566x over previous
//
#include <hip/hip_runtime.h>

#define N_NODES 81920
#define N_EDGES 1310720
#define NG 256
#define D 64
#define TM 64
#define SA 65            // LDS row stride: 2-way bank alias max (free)
#define NB 320           // 256-thread node blocks covering N_NODES
#define NBLK 1280        // src blocks of 64 nodes
#define BMW 2560         // bitmask words (81920/32)
#define RPW 1296         // padded row_ptr stride (>= NBLK+1)
#define HCHUNK 32768     // edges per histogram/bucket workgroup (40 WGs)

__device__ __forceinline__ bool tb(const unsigned* bm, int i) {
    return (bm[i >> 5] >> (i & 31)) & 1u;
}

// ---------------- tiny utility kernels ----------------

__global__ void zero_ints(int* __restrict__ p, int n) {
    int i = blockIdx.x * blockDim.x + threadIdx.x;
    if (i < n) p[i] = 0;
}

__global__ void zero_f4(float4* __restrict__ p, int n4) {
    int i = blockIdx.x * blockDim.x + threadIdx.x;
    if (i < n4) p[i] = make_float4(0.f, 0.f, 0.f, 0.f);
}

__global__ void find_first(const int* __restrict__ batch, int* __restrict__ fidx) {
    int i = blockIdx.x * blockDim.x + threadIdx.x;
    if (i < N_NODES) {
        int b = batch[i];
        if (i == 0 || batch[i - 1] != b) fidx[b] = i;
    }
}

__global__ void mark_set_bm(const int* __restrict__ fidx, unsigned* __restrict__ bm2,
                            unsigned* __restrict__ bm1) {
    int n = fidx[threadIdx.x];            // 1 block x 256
    atomicOr(&bm2[n >> 5], 1u << (n & 31));
    atomicOr(&bm1[n >> 5], 1u << (n & 31));
}

// mark srcs of edges with dst-bit set in bmD into bmS; optionally OR-copy orsrc into bmS
__global__ void mark_srcs_bm(const int* __restrict__ src, const int* __restrict__ dst,
                             const unsigned* __restrict__ bmD, unsigned* __restrict__ bmS,
                             const unsigned* __restrict__ orsrc) {
    if (orsrc && blockIdx.x == 0) {
        for (int w = threadIdx.x; w < BMW; w += 256)
            if (orsrc[w]) atomicOr(&bmS[w], orsrc[w]);
    }
    int e = blockIdx.x * 256 + threadIdx.x;
    if (e < N_EDGES && tb(bmD, dst[e])) {
        int s = src[e];
        atomicOr(&bmS[s >> 5], 1u << (s & 31));
    }
}

// compact two bitmasks -> node lists (order irrelevant)
__global__ void compact2_bm(const unsigned* __restrict__ bm0, const unsigned* __restrict__ bm1,
                            int* __restrict__ list0, int* __restrict__ list1,
                            int* __restrict__ n0, int* __restrict__ n1) {
    int i = blockIdx.x * 256 + threadIdx.x;
    int lane = threadIdx.x & 63;
    bool p0 = tb(bm0, i);
    bool p1 = tb(bm1, i);
    unsigned long long b0 = __ballot(p0);
    int lt = __popcll(b0 & ((1ull << lane) - 1));
    int base = 0;
    if (lane == 0 && b0) base = atomicAdd(n0, __popcll(b0));
    base = __shfl(base, 0);
    if (p0) list0[base + lt] = i;
    unsigned long long b1 = __ballot(p1);
    lt = __popcll(b1 & ((1ull << lane) - 1));
    base = 0;
    if (lane == 0 && b1) base = atomicAdd(n1, __popcll(b1));
    base = __shfl(base, 0);
    if (p1) list1[base + lt] = i;
}

// per-src-block counts for the three layers (LDS histograms + sparse merge)
// + exact in-degree for masked dsts (global fire-and-forget atomics; for d in m0
//   ALL in-edges pass the filter, so the masked count == full in-degree)
__global__ __launch_bounds__(256) void hist_cnt(const int* __restrict__ src,
                                                const int* __restrict__ dst,
                                                const unsigned* __restrict__ bm0,
                                                const unsigned* __restrict__ bm1,
                                                const unsigned* __restrict__ bm2,
                                                int* __restrict__ cnt3b,
                                                int* __restrict__ indeg) {
    __shared__ int h0[NBLK], h1[NBLK], h2[NBLK];
    const int e0 = blockIdx.x * HCHUNK;   // 40 WGs
    for (int i = threadIdx.x; i < NBLK; i += 256) { h0[i] = 0; h1[i] = 0; h2[i] = 0; }
    __syncthreads();
    for (int e = e0 + threadIdx.x; e < e0 + HCHUNK; e += 256) {
        int d = dst[e];
        if (tb(bm0, d)) {
            int sb = src[e] >> 6;
            atomicAdd(&indeg[d], 1);      // fire-and-forget, L2-resident 188 KB
            atomicAdd(&h0[sb], 1);
            if (tb(bm1, d)) {
                atomicAdd(&h1[sb], 1);
                if (tb(bm2, d)) atomicAdd(&h2[sb], 1);
            }
        }
    }
    __syncthreads();
    for (int i = threadIdx.x; i < NBLK; i += 256) {
        if (h0[i]) atomicAdd(&cnt3b[i], h0[i]);
        if (h1[i]) atomicAdd(&cnt3b[NBLK + i], h1[i]);
        if (h2[i]) atomicAdd(&cnt3b[2 * NBLK + i], h2[i]);
    }
}

// exclusive scan of 1280 counts x3 -> row_ptr + cursor init
__global__ void scan1280(const int* __restrict__ cnt3b, int* __restrict__ rp3b,
                         int* __restrict__ cur3b) {
    const int a = blockIdx.x;             // 3 blocks
    const int* c = cnt3b + a * NBLK;
    int* rp = rp3b + a * RPW;
    int* cu = cur3b + a * RPW;
    __shared__ int s[256];
    __shared__ int carry;
    int tid = threadIdx.x;
    if (tid == 0) carry = 0;
    __syncthreads();
    for (int r = 0; r < NBLK / 256; ++r) {
        int i = r * 256 + tid;
        int v = c[i];
        s[tid] = v;
        __syncthreads();
        for (int ofs = 1; ofs < 256; ofs <<= 1) {
            int t = (tid >= ofs) ? s[tid - ofs] : 0;
            __syncthreads();
            s[tid] += t;
            __syncthreads();
        }
        int excl = s[tid] - v + carry;
        rp[i] = excl;
        cu[i] = excl;
        __syncthreads();
        if (tid == 255) carry += s[255];
        __syncthreads();
    }
    if (tid == 0) rp[NBLK] = carry;
}

// bucket all three layers: per-WG LDS histogram -> bulk chunk reservation -> place
__global__ __launch_bounds__(256) void bucket3(const int* __restrict__ src,
                                               const int* __restrict__ dst,
                                               const unsigned* __restrict__ bm0,
                                               const unsigned* __restrict__ bm1,
                                               const unsigned* __restrict__ bm2,
                                               int* __restrict__ cur3b,
                                               int* __restrict__ esp0,
                                               int* __restrict__ esp1,
                                               int* __restrict__ esp2) {
    __shared__ int h0[NBLK], h1[NBLK], h2[NBLK];
    const int e0 = blockIdx.x * HCHUNK;   // 40 WGs
    for (int i = threadIdx.x; i < NBLK; i += 256) { h0[i] = 0; h1[i] = 0; h2[i] = 0; }
    __syncthreads();
    for (int e = e0 + threadIdx.x; e < e0 + HCHUNK; e += 256) {
        int d = dst[e];
        if (tb(bm0, d)) {
            int sb = src[e] >> 6;
            atomicAdd(&h0[sb], 1);
            if (tb(bm1, d)) {
                atomicAdd(&h1[sb], 1);
                if (tb(bm2, d)) atomicAdd(&h2[sb], 1);
            }
        }
    }
    __syncthreads();
    for (int i = threadIdx.x; i < NBLK; i += 256) {   // bulk-reserve chunks
        int c = h0[i]; h0[i] = c ? atomicAdd(&cur3b[i], c) : 0;
        c = h1[i];     h1[i] = c ? atomicAdd(&cur3b[RPW + i], c) : 0;
        c = h2[i];     h2[i] = c ? atomicAdd(&cur3b[2 * RPW + i], c) : 0;
    }
    __syncthreads();
    for (int e = e0 + threadIdx.x; e < e0 + HCHUNK; e += 256) {
        int d = dst[e];
        if (tb(bm0, d)) {
            int s = src[e];
            int sb = s >> 6;
            int pk = (d << 6) | (s & 63);
            int pos = atomicAdd(&h0[sb], 1);          // LDS cursor
            esp0[pos] = pk;
            if (tb(bm1, d)) {
                pos = atomicAdd(&h1[sb], 1);
                esp1[pos] = pk;
                if (tb(bm2, d)) {
                    pos = atomicAdd(&h2[sb], 1);
                    esp2[pos] = pk;
                }
            }
        }
    }
}

// ---------------- push phase: LDS-staged rows + fire-and-forget scatter atomics ----

__global__ __launch_bounds__(256, 8) void sage_push(
    const float* __restrict__ hin, const int* __restrict__ row_ptr,
    const int* __restrict__ esp, float* __restrict__ agg)
{
    __shared__ float Rs[TM * SA];     // this block's 64 src rows

    const int tid  = threadIdx.x;
    const int base = blockIdx.x * TM;
    const int lane = tid & 63;
    const int w    = tid >> 6;

    const int e0 = row_ptr[blockIdx.x];
    const int e1 = row_ptr[blockIdx.x + 1];
    if (e0 == e1) return;             // nothing to push from this block

    for (int idx = tid; idx < TM * D; idx += 256) {
        int m = idx >> 6, k = idx & 63;
        Rs[m * SA + k] = hin[(base << 6) + idx];   // coalesced stream
    }
    __syncthreads();

    const int chunk = ((e1 - e0) + 3) >> 2;
    int e = e0 + w * chunk;
    const int ee = min(e + chunk, e1);

    for (; e + 64 <= ee; e += 64) {
        int pv = esp[e + lane];                    // 64 edges, one coalesced load
        #pragma unroll
        for (int u = 0; u < 64; ++u) {
            int p = __shfl(pv, u);                 // broadcast edge u
            float v = Rs[(p & 63) * SA + lane];    // LDS row read, 2-way alias
            atomicAdd(&agg[(p & 0x7fffffc0) + lane], v);  // fire-and-forget f32 atomic
        }
    }
    for (; e < ee; ++e) {
        int p = esp[e];
        atomicAdd(&agg[(p & 0x7fffffc0) + lane], Rs[(p & 63) * SA + lane]);
    }
}

// ---------------- finish on a compacted node list: scale + dual fp32 GEMM + re-zero ----

__global__ __launch_bounds__(256, 4) void sage_finish_sel(
    const float* __restrict__ hin, float* __restrict__ agg,
    const int* __restrict__ indeg, const int* __restrict__ list,
    const int* __restrict__ pcount, float* __restrict__ hout,
    const float* __restrict__ Wl, const float* __restrict__ bl,
    const float* __restrict__ Wr, int relu)
{
    __shared__ float As[TM * SA];
    __shared__ float Xs[TM * SA];
    __shared__ float invs[TM];
    __shared__ int   nid[TM];

    const int cntv = *pcount;
    const int base = blockIdx.x * TM;
    if (base >= cntv) return;

    const int tid = threadIdx.x;
    if (tid < TM) {
        int n = (base + tid < cntv) ? list[base + tid] : -1;
        nid[tid]  = n;
        invs[tid] = (n >= 0) ? 1.0f / (float)max(indeg[n], 1) : 0.f;
    }
    __syncthreads();
    for (int idx = tid; idx < TM * D; idx += 256) {
        int m = idx >> 6, k = idx & 63;
        int n = nid[m];
        if (n >= 0) {
            As[m * SA + k] = agg[n * D + k] * invs[m];
            Xs[m * SA + k] = hin[n * D + k];
            agg[n * D + k] = 0.0f;                 // re-zero for the next push phase
        } else {
            As[m * SA + k] = 0.f;
            Xs[m * SA + k] = 0.f;
        }
    }
    __syncthreads();

    const int j0 = (tid & 15) << 2;
    const int m0 = (tid >> 4) << 2;
    float o[4][4];
    float4 b4 = *(const float4*)&bl[j0];
    #pragma unroll
    for (int mi = 0; mi < 4; ++mi) {
        o[mi][0] = b4.x; o[mi][1] = b4.y; o[mi][2] = b4.z; o[mi][3] = b4.w;
    }
    #pragma unroll 8
    for (int k = 0; k < D; ++k) {
        float4 wl = *(const float4*)&Wl[(k << 6) + j0];   // global, L1-resident broadcast
        float4 wr = *(const float4*)&Wr[(k << 6) + j0];
        #pragma unroll
        for (int mi = 0; mi < 4; ++mi) {
            float a = As[(m0 + mi) * SA + k];
            float x = Xs[(m0 + mi) * SA + k];
            o[mi][0] += a * wl.x + x * wr.x;
            o[mi][1] += a * wl.y + x * wr.y;
            o[mi][2] += a * wl.z + x * wr.z;
            o[mi][3] += a * wl.w + x * wr.w;
        }
    }
    #pragma unroll
    for (int mi = 0; mi < 4; ++mi) {
        int n = nid[m0 + mi];
        if (n >= 0) {
            float4 r = make_float4(o[mi][0], o[mi][1], o[mi][2], o[mi][3]);
            if (relu) {
                r.x = fmaxf(r.x, 0.f); r.y = fmaxf(r.y, 0.f);
                r.z = fmaxf(r.z, 0.f); r.w = fmaxf(r.w, 0.f);
            }
            *(float4*)&hout[n * D + j0] = r;
        }
    }
}

// ---------------- final layer GEMM on the 256 selected nodes ----------------

__global__ __launch_bounds__(256, 3) void final_gemm_sel(
    const float* __restrict__ hin, const float* __restrict__ agg,
    const int* __restrict__ indeg, const int* __restrict__ fidx,
    const float* __restrict__ Wl, const float* __restrict__ bl,
    const float* __restrict__ Wr, float* __restrict__ out)
{
    __shared__ float As[TM * SA];
    __shared__ float Xs[TM * SA];
    __shared__ int   nid[TM];
    __shared__ float invs[TM];

    const int tid  = threadIdx.x;
    const int base = blockIdx.x * TM;

    if (tid < TM) {
        int n = fidx[base + tid];
        nid[tid]  = n;
        invs[tid] = 1.0f / (float)max(indeg[n], 1);
    }
    __syncthreads();
    for (int idx = tid; idx < TM * D; idx += 256) {
        int m = idx >> 6, k = idx & 63;
        int n = nid[m];
        As[m * SA + k] = agg[n * D + k] * invs[m];
        Xs[m * SA + k] = hin[n * D + k];
    }
    __syncthreads();

    const int j0 = (tid & 15) << 2;
    const int m0 = (tid >> 4) << 2;
    float o[4][4];
    float4 b4 = *(const float4*)&bl[j0];
    #pragma unroll
    for (int mi = 0; mi < 4; ++mi) {
        o[mi][0] = b4.x; o[mi][1] = b4.y; o[mi][2] = b4.z; o[mi][3] = b4.w;
    }
    #pragma unroll 8
    for (int k = 0; k < D; ++k) {
        float4 wl = *(const float4*)&Wl[(k << 6) + j0];
        float4 wr = *(const float4*)&Wr[(k << 6) + j0];
        #pragma unroll
        for (int mi = 0; mi < 4; ++mi) {
            float a = As[(m0 + mi) * SA + k];
            float x = Xs[(m0 + mi) * SA + k];
            o[mi][0] += a * wl.x + x * wr.x;
            o[mi][1] += a * wl.y + x * wr.y;
            o[mi][2] += a * wl.z + x * wr.z;
            o[mi][3] += a * wl.w + x * wr.w;
        }
    }
    #pragma unroll
    for (int mi = 0; mi < 4; ++mi) {
        float4 r = make_float4(o[mi][0], o[mi][1], o[mi][2], o[mi][3]);
        *(float4*)&out[(base + m0 + mi) * D + j0] = r;
    }
}

// ---------------- launch ----------------

extern "C" void kernel_launch(void* const* d_in, const int* in_sizes, int n_in,
                              void* d_out, int out_size, void* d_ws, size_t ws_size,
                              hipStream_t stream)
{
    const float* x     = (const float*)d_in[0];
    const int*   ei    = (const int*)d_in[1];
    const int*   batch = (const int*)d_in[2];
    const float* Wl0 = (const float*)d_in[3];
    const float* bl0 = (const float*)d_in[4];
    const float* Wr0 = (const float*)d_in[5];
    const float* Wl1 = (const float*)d_in[6];
    const float* bl1 = (const float*)d_in[7];
    const float* Wr1 = (const float*)d_in[8];
    const float* Wl2 = (const float*)d_in[9];
    const float* bl2 = (const float*)d_in[10];
    const float* Wr2 = (const float*)d_in[11];
    float* out = (float*)d_out;

    const int* src = ei;             // edge_index[0]
    const int* dst = ei + N_EDGES;   // edge_index[1]

    char* ws = (char*)d_ws;
    size_t off = 0;
    auto alloc = [&](size_t bytes) -> void* {
        void* p = ws + off;
        off = (off + bytes + 255) & ~(size_t)255;
        return p;
    };
    int*   rp3b    = (int*)alloc((size_t)3 * RPW * sizeof(int));
    int*   cur3b   = (int*)alloc((size_t)3 * RPW * sizeof(int));
    int*   fidx    = (int*)alloc(NG * sizeof(int));
    int*   list0   = (int*)alloc(N_NODES * sizeof(int));
    int*   list1   = (int*)alloc(N_NODES * sizeof(int));
    int*   esp0    = (int*)alloc((size_t)N_EDGES * sizeof(int));
    int*   esp1    = (int*)alloc((size_t)(N_EDGES / 4) * sizeof(int));   // ~69K expected
    int*   esp2    = (int*)alloc((size_t)(N_EDGES / 16) * sizeof(int));  // ~4K expected
    float* agg     = (float*)alloc((size_t)N_NODES * D * sizeof(float));
    float* h1      = (float*)alloc((size_t)N_NODES * D * sizeof(float));
    float* h2      = (float*)alloc((size_t)N_NODES * D * sizeof(float));
    // zeroable: bm0|bm1|bm2, cnt3b, indeg, n0, n1
    const int ZN   = 3 * BMW + 3 * NBLK + N_NODES + 64;
    int*   zbase   = (int*)alloc((size_t)ZN * sizeof(int));
    unsigned* bm0  = (unsigned*)zbase;
    unsigned* bm1  = (unsigned*)(zbase + BMW);
    unsigned* bm2  = (unsigned*)(zbase + 2 * BMW);
    int* cnt3b = zbase + 3 * BMW;
    int* indeg = zbase + 3 * BMW + 3 * NBLK;
    int* n0    = indeg + N_NODES;
    int* n1    = n0 + 1;
    (void)ws_size; (void)in_sizes; (void)n_in; (void)out_size;

    const int EB = (N_EDGES + 255) / 256;   // 5120

    zero_f4   <<<(N_NODES * D / 4 + 255) / 256, 256, 0, stream>>>((float4*)agg, N_NODES * D / 4);
    zero_ints <<<(ZN + 255) / 256, 256, 0, stream>>>(zbase, ZN);
    find_first<<<NB, 256, 0, stream>>>(batch, fidx);

    // masks (bitmasks): bm2 = outputs; bm1 = bm2 ∪ src(dst∈bm2); bm0 = bm1 ∪ src(dst∈bm1)
    mark_set_bm <<<1, NG, 0, stream>>>(fidx, bm2, bm1);
    mark_srcs_bm<<<EB, 256, 0, stream>>>(src, dst, bm2, bm1, (const unsigned*)nullptr);
    mark_srcs_bm<<<EB, 256, 0, stream>>>(src, dst, bm1, bm0, bm1);   // incl. OR-copy bm1->bm0
    compact2_bm <<<NB, 256, 0, stream>>>(bm0, bm1, list0, list1, n0, n1);

    // CSR build + exact in-degree (one edge pass each)
    hist_cnt  <<<40, 256, 0, stream>>>(src, dst, bm0, bm1, bm2, cnt3b, indeg);
    scan1280  <<<3, 256, 0, stream>>>(cnt3b, rp3b, cur3b);
    bucket3   <<<40, 256, 0, stream>>>(src, dst, bm0, bm1, bm2, cur3b, esp0, esp1, esp2);

    // layer 0: push dst∈m0, finish on m0 list
    sage_push      <<<NBLK, 256, 0, stream>>>(x, rp3b, esp0, agg);
    sage_finish_sel<<<NBLK, 256, 0, stream>>>(x, agg, indeg, list0, n0,
                                              h1, Wl0, bl0, Wr0, 1);
    // layer 1: push dst∈m1, finish on m1 list
    sage_push      <<<NBLK, 256, 0, stream>>>(h1, rp3b + RPW, esp1, agg);
    sage_finish_sel<<<NBLK, 256, 0, stream>>>(h1, agg, indeg, list1, n1,
                                              h2, Wl1, bl1, Wr1, 1);
    // layer 2: push dst∈m2, GEMM on the 256 output nodes
    sage_push      <<<NBLK, 256, 0, stream>>>(h2, rp3b + 2 * RPW, esp2, agg);
    final_gemm_sel <<<NG / TM, 256, 0, stream>>>(h2, agg, indeg, fidx, Wl2, bl2, Wr2, out);
}

// Round 9
// 521.655 us; speedup vs baseline: 3.9375x; 1.4284x over previous
//
#include <hip/hip_runtime.h>

#define N_NODES 81920
#define N_EDGES 1310720
#define NG 256
#define D 64
#define TM 64
#define SA 65            // LDS row stride: 2-way bank alias max (free)
#define NB 320           // 256-thread node blocks covering N_NODES
#define NBLK 1280        // src blocks of 64 nodes
#define BMW 2560         // bitmask words (81920/32)
#define RPW 1296         // padded row_ptr stride (>= NBLK+1)
#define HWGS 320         // histogram/bucket workgroups
#define HCHUNK 4096      // edges per WG (HWGS*HCHUNK == N_EDGES)

__device__ __forceinline__ bool tb(const unsigned* bm, int i) {
    return (bm[i >> 5] >> (i & 31)) & 1u;
}

// ---------------- tiny utility kernels ----------------

__global__ void zero_ints(int* __restrict__ p, int n) {
    int i = blockIdx.x * blockDim.x + threadIdx.x;
    if (i < n) p[i] = 0;
}

__global__ void zero_f4(float4* __restrict__ p, int n4) {
    int i = blockIdx.x * blockDim.x + threadIdx.x;
    if (i < n4) p[i] = make_float4(0.f, 0.f, 0.f, 0.f);
}

__global__ void find_first(const int* __restrict__ batch, int* __restrict__ fidx) {
    int i = blockIdx.x * blockDim.x + threadIdx.x;
    if (i < N_NODES) {
        int b = batch[i];
        if (i == 0 || batch[i - 1] != b) fidx[b] = i;
    }
}

__global__ void mark_set_bm(const int* __restrict__ fidx, unsigned* __restrict__ bm2,
                            unsigned* __restrict__ bm1) {
    int n = fidx[threadIdx.x];            // 1 block x 256
    atomicOr(&bm2[n >> 5], 1u << (n & 31));
    atomicOr(&bm1[n >> 5], 1u << (n & 31));
}

// mark srcs of edges with dst-bit set in bmD into bmS; optionally OR-copy orsrc into bmS
__global__ void mark_srcs_bm(const int* __restrict__ src, const int* __restrict__ dst,
                             const unsigned* __restrict__ bmD, unsigned* __restrict__ bmS,
                             const unsigned* __restrict__ orsrc) {
    if (orsrc && blockIdx.x == 0) {
        for (int w = threadIdx.x; w < BMW; w += 256)
            if (orsrc[w]) atomicOr(&bmS[w], orsrc[w]);
    }
    int e = blockIdx.x * 256 + threadIdx.x;
    if (e < N_EDGES && tb(bmD, dst[e])) {
        int s = src[e];
        atomicOr(&bmS[s >> 5], 1u << (s & 31));
    }
}

// compact two bitmasks -> node lists (order irrelevant)
__global__ void compact2_bm(const unsigned* __restrict__ bm0, const unsigned* __restrict__ bm1,
                            int* __restrict__ list0, int* __restrict__ list1,
                            int* __restrict__ n0, int* __restrict__ n1) {
    int i = blockIdx.x * 256 + threadIdx.x;
    int lane = threadIdx.x & 63;
    bool p0 = tb(bm0, i);
    bool p1 = tb(bm1, i);
    unsigned long long b0 = __ballot(p0);
    int lt = __popcll(b0 & ((1ull << lane) - 1));
    int base = 0;
    if (lane == 0 && b0) base = atomicAdd(n0, __popcll(b0));
    base = __shfl(base, 0);
    if (p0) list0[base + lt] = i;
    unsigned long long b1 = __ballot(p1);
    lt = __popcll(b1 & ((1ull << lane) - 1));
    base = 0;
    if (lane == 0 && b1) base = atomicAdd(n1, __popcll(b1));
    base = __shfl(base, 0);
    if (p1) list1[base + lt] = i;
}

// per-src-block counts for the three layers (LDS histograms + sparse merge)
// + exact in-degree for masked dsts (for d in m0 ALL in-edges pass, so count is exact)
__global__ __launch_bounds__(256) void hist_cnt(const int* __restrict__ src,
                                                const int* __restrict__ dst,
                                                const unsigned* __restrict__ bm0,
                                                const unsigned* __restrict__ bm1,
                                                const unsigned* __restrict__ bm2,
                                                int* __restrict__ cnt3b,
                                                int* __restrict__ indeg) {
    __shared__ int h0[NBLK], h1[NBLK], h2[NBLK];
    const int e0 = blockIdx.x * HCHUNK;   // HWGS WGs
    for (int i = threadIdx.x; i < NBLK; i += 256) { h0[i] = 0; h1[i] = 0; h2[i] = 0; }
    __syncthreads();
    for (int e = e0 + threadIdx.x; e < e0 + HCHUNK; e += 256) {
        int d = dst[e];
        if (tb(bm0, d)) {
            int sb = src[e] >> 6;
            atomicAdd(&indeg[d], 1);      // fire-and-forget, L2-resident 320 KB
            atomicAdd(&h0[sb], 1);
            if (tb(bm1, d)) {
                atomicAdd(&h1[sb], 1);
                if (tb(bm2, d)) atomicAdd(&h2[sb], 1);
            }
        }
    }
    __syncthreads();
    for (int i = threadIdx.x; i < NBLK; i += 256) {
        if (h0[i]) atomicAdd(&cnt3b[i], h0[i]);
        if (h1[i]) atomicAdd(&cnt3b[NBLK + i], h1[i]);
        if (h2[i]) atomicAdd(&cnt3b[2 * NBLK + i], h2[i]);
    }
}

// exclusive scan of 1280 counts x3 -> row_ptr + cursor init
__global__ void scan1280(const int* __restrict__ cnt3b, int* __restrict__ rp3b,
                         int* __restrict__ cur3b) {
    const int a = blockIdx.x;             // 3 blocks
    const int* c = cnt3b + a * NBLK;
    int* rp = rp3b + a * RPW;
    int* cu = cur3b + a * RPW;
    __shared__ int s[256];
    __shared__ int carry;
    int tid = threadIdx.x;
    if (tid == 0) carry = 0;
    __syncthreads();
    for (int r = 0; r < NBLK / 256; ++r) {
        int i = r * 256 + tid;
        int v = c[i];
        s[tid] = v;
        __syncthreads();
        for (int ofs = 1; ofs < 256; ofs <<= 1) {
            int t = (tid >= ofs) ? s[tid - ofs] : 0;
            __syncthreads();
            s[tid] += t;
            __syncthreads();
        }
        int excl = s[tid] - v + carry;
        rp[i] = excl;
        cu[i] = excl;
        __syncthreads();
        if (tid == 255) carry += s[255];
        __syncthreads();
    }
    if (tid == 0) rp[NBLK] = carry;
}

// bucket all three layers: per-WG LDS histogram -> bulk chunk reservation -> place
__global__ __launch_bounds__(256) void bucket3(const int* __restrict__ src,
                                               const int* __restrict__ dst,
                                               const unsigned* __restrict__ bm0,
                                               const unsigned* __restrict__ bm1,
                                               const unsigned* __restrict__ bm2,
                                               int* __restrict__ cur3b,
                                               int* __restrict__ esp0,
                                               int* __restrict__ esp1,
                                               int* __restrict__ esp2) {
    __shared__ int h0[NBLK], h1[NBLK], h2[NBLK];
    const int e0 = blockIdx.x * HCHUNK;   // HWGS WGs
    for (int i = threadIdx.x; i < NBLK; i += 256) { h0[i] = 0; h1[i] = 0; h2[i] = 0; }
    __syncthreads();
    for (int e = e0 + threadIdx.x; e < e0 + HCHUNK; e += 256) {
        int d = dst[e];
        if (tb(bm0, d)) {
            int sb = src[e] >> 6;
            atomicAdd(&h0[sb], 1);
            if (tb(bm1, d)) {
                atomicAdd(&h1[sb], 1);
                if (tb(bm2, d)) atomicAdd(&h2[sb], 1);
            }
        }
    }
    __syncthreads();
    for (int i = threadIdx.x; i < NBLK; i += 256) {   // bulk-reserve chunks
        int c = h0[i]; h0[i] = c ? atomicAdd(&cur3b[i], c) : 0;
        c = h1[i];     h1[i] = c ? atomicAdd(&cur3b[RPW + i], c) : 0;
        c = h2[i];     h2[i] = c ? atomicAdd(&cur3b[2 * RPW + i], c) : 0;
    }
    __syncthreads();
    for (int e = e0 + threadIdx.x; e < e0 + HCHUNK; e += 256) {
        int d = dst[e];
        if (tb(bm0, d)) {
            int s = src[e];
            int sb = s >> 6;
            int pk = (d << 6) | (s & 63);
            int pos = atomicAdd(&h0[sb], 1);          // LDS cursor
            esp0[pos] = pk;
            if (tb(bm1, d)) {
                pos = atomicAdd(&h1[sb], 1);
                esp1[pos] = pk;
                if (tb(bm2, d)) {
                    pos = atomicAdd(&h2[sb], 1);
                    esp2[pos] = pk;
                }
            }
        }
    }
}

// ---------------- push phase: LDS-staged rows + fire-and-forget scatter atomics ----

__global__ __launch_bounds__(256, 8) void sage_push(
    const float* __restrict__ hin, const int* __restrict__ row_ptr,
    const int* __restrict__ esp, float* __restrict__ agg)
{
    __shared__ float Rs[TM * SA];     // this block's 64 src rows

    const int tid  = threadIdx.x;
    const int base = blockIdx.x * TM;
    const int lane = tid & 63;
    const int w    = tid >> 6;

    const int e0 = row_ptr[blockIdx.x];
    const int e1 = row_ptr[blockIdx.x + 1];
    if (e0 == e1) return;             // nothing to push from this block

    for (int idx = tid; idx < TM * D; idx += 256) {
        int m = idx >> 6, k = idx & 63;
        Rs[m * SA + k] = hin[(base << 6) + idx];   // coalesced stream
    }
    __syncthreads();

    const int chunk = ((e1 - e0) + 3) >> 2;
    int e = e0 + w * chunk;
    const int ee = min(e + chunk, e1);

    for (; e + 64 <= ee; e += 64) {
        int pv = esp[e + lane];                    // 64 edges, one coalesced load
        #pragma unroll
        for (int u = 0; u < 64; ++u) {
            int p = __shfl(pv, u);                 // broadcast edge u
            float v = Rs[(p & 63) * SA + lane];    // LDS row read, 2-way alias
            atomicAdd(&agg[(p & 0x7fffffc0) + lane], v);  // fire-and-forget f32 atomic
        }
    }
    for (; e < ee; ++e) {
        int p = esp[e];
        atomicAdd(&agg[(p & 0x7fffffc0) + lane], Rs[(p & 63) * SA + lane]);
    }
}

// ---------------- finish on a compacted node list: scale + dual fp32 GEMM + re-zero ----

__global__ __launch_bounds__(256, 4) void sage_finish_sel(
    const float* __restrict__ hin, float* __restrict__ agg,
    const int* __restrict__ indeg, const int* __restrict__ list,
    const int* __restrict__ pcount, float* __restrict__ hout,
    const float* __restrict__ Wl, const float* __restrict__ bl,
    const float* __restrict__ Wr, int relu)
{
    __shared__ float As[TM * SA];
    __shared__ float Xs[TM * SA];
    __shared__ float invs[TM];
    __shared__ int   nid[TM];

    const int cntv = *pcount;
    const int base = blockIdx.x * TM;
    if (base >= cntv) return;

    const int tid = threadIdx.x;
    if (tid < TM) {
        int n = (base + tid < cntv) ? list[base + tid] : -1;
        nid[tid]  = n;
        invs[tid] = (n >= 0) ? 1.0f / (float)max(indeg[n], 1) : 0.f;
    }
    __syncthreads();
    for (int idx = tid; idx < TM * D; idx += 256) {
        int m = idx >> 6, k = idx & 63;
        int n = nid[m];
        if (n >= 0) {
            As[m * SA + k] = agg[n * D + k] * invs[m];
            Xs[m * SA + k] = hin[n * D + k];
            agg[n * D + k] = 0.0f;                 // re-zero for the next push phase
        } else {
            As[m * SA + k] = 0.f;
            Xs[m * SA + k] = 0.f;
        }
    }
    __syncthreads();

    const int j0 = (tid & 15) << 2;
    const int m0 = (tid >> 4) << 2;
    float o[4][4];
    float4 b4 = *(const float4*)&bl[j0];
    #pragma unroll
    for (int mi = 0; mi < 4; ++mi) {
        o[mi][0] = b4.x; o[mi][1] = b4.y; o[mi][2] = b4.z; o[mi][3] = b4.w;
    }
    #pragma unroll 8
    for (int k = 0; k < D; ++k) {
        float4 wl = *(const float4*)&Wl[(k << 6) + j0];   // global, L1-resident broadcast
        float4 wr = *(const float4*)&Wr[(k << 6) + j0];
        #pragma unroll
        for (int mi = 0; mi < 4; ++mi) {
            float a = As[(m0 + mi) * SA + k];
            float x = Xs[(m0 + mi) * SA + k];
            o[mi][0] += a * wl.x + x * wr.x;
            o[mi][1] += a * wl.y + x * wr.y;
            o[mi][2] += a * wl.z + x * wr.z;
            o[mi][3] += a * wl.w + x * wr.w;
        }
    }
    #pragma unroll
    for (int mi = 0; mi < 4; ++mi) {
        int n = nid[m0 + mi];
        if (n >= 0) {
            float4 r = make_float4(o[mi][0], o[mi][1], o[mi][2], o[mi][3]);
            if (relu) {
                r.x = fmaxf(r.x, 0.f); r.y = fmaxf(r.y, 0.f);
                r.z = fmaxf(r.z, 0.f); r.w = fmaxf(r.w, 0.f);
            }
            *(float4*)&hout[n * D + j0] = r;
        }
    }
}

// ---------------- final layer GEMM on the 256 selected nodes ----------------

__global__ __launch_bounds__(256, 3) void final_gemm_sel(
    const float* __restrict__ hin, const float* __restrict__ agg,
    const int* __restrict__ indeg, const int* __restrict__ fidx,
    const float* __restrict__ Wl, const float* __restrict__ bl,
    const float* __restrict__ Wr, float* __restrict__ out)
{
    __shared__ float As[TM * SA];
    __shared__ float Xs[TM * SA];
    __shared__ int   nid[TM];
    __shared__ float invs[TM];

    const int tid  = threadIdx.x;
    const int base = blockIdx.x * TM;

    if (tid < TM) {
        int n = fidx[base + tid];
        nid[tid]  = n;
        invs[tid] = 1.0f / (float)max(indeg[n], 1);
    }
    __syncthreads();
    for (int idx = tid; idx < TM * D; idx += 256) {
        int m = idx >> 6, k = idx & 63;
        int n = nid[m];
        As[m * SA + k] = agg[n * D + k] * invs[m];
        Xs[m * SA + k] = hin[n * D + k];
    }
    __syncthreads();

    const int j0 = (tid & 15) << 2;
    const int m0 = (tid >> 4) << 2;
    float o[4][4];
    float4 b4 = *(const float4*)&bl[j0];
    #pragma unroll
    for (int mi = 0; mi < 4; ++mi) {
        o[mi][0] = b4.x; o[mi][1] = b4.y; o[mi][2] = b4.z; o[mi][3] = b4.w;
    }
    #pragma unroll 8
    for (int k = 0; k < D; ++k) {
        float4 wl = *(const float4*)&Wl[(k << 6) + j0];
        float4 wr = *(const float4*)&Wr[(k << 6) + j0];
        #pragma unroll
        for (int mi = 0; mi < 4; ++mi) {
            float a = As[(m0 + mi) * SA + k];
            float x = Xs[(m0 + mi) * SA + k];
            o[mi][0] += a * wl.x + x * wr.x;
            o[mi][1] += a * wl.y + x * wr.y;
            o[mi][2] += a * wl.z + x * wr.z;
            o[mi][3] += a * wl.w + x * wr.w;
        }
    }
    #pragma unroll
    for (int mi = 0; mi < 4; ++mi) {
        float4 r = make_float4(o[mi][0], o[mi][1], o[mi][2], o[mi][3]);
        *(float4*)&out[(base + m0 + mi) * D + j0] = r;
    }
}

// ---------------- launch ----------------

extern "C" void kernel_launch(void* const* d_in, const int* in_sizes, int n_in,
                              void* d_out, int out_size, void* d_ws, size_t ws_size,
                              hipStream_t stream)
{
    const float* x     = (const float*)d_in[0];
    const int*   ei    = (const int*)d_in[1];
    const int*   batch = (const int*)d_in[2];
    const float* Wl0 = (const float*)d_in[3];
    const float* bl0 = (const float*)d_in[4];
    const float* Wr0 = (const float*)d_in[5];
    const float* Wl1 = (const float*)d_in[6];
    const float* bl1 = (const float*)d_in[7];
    const float* Wr1 = (const float*)d_in[8];
    const float* Wl2 = (const float*)d_in[9];
    const float* bl2 = (const float*)d_in[10];
    const float* Wr2 = (const float*)d_in[11];
    float* out = (float*)d_out;

    const int* src = ei;             // edge_index[0]
    const int* dst = ei + N_EDGES;   // edge_index[1]

    char* ws = (char*)d_ws;
    size_t off = 0;
    auto alloc = [&](size_t bytes) -> void* {
        void* p = ws + off;
        off = (off + bytes + 255) & ~(size_t)255;
        return p;
    };
    int*   rp3b    = (int*)alloc((size_t)3 * RPW * sizeof(int));
    int*   cur3b   = (int*)alloc((size_t)3 * RPW * sizeof(int));
    int*   fidx    = (int*)alloc(NG * sizeof(int));
    int*   list0   = (int*)alloc(N_NODES * sizeof(int));
    int*   list1   = (int*)alloc(N_NODES * sizeof(int));
    int*   esp0    = (int*)alloc((size_t)N_EDGES * sizeof(int));
    int*   esp1    = (int*)alloc((size_t)(N_EDGES / 4) * sizeof(int));   // ~69K expected
    int*   esp2    = (int*)alloc((size_t)(N_EDGES / 16) * sizeof(int));  // ~4K expected
    float* agg     = (float*)alloc((size_t)N_NODES * D * sizeof(float));
    float* h1      = (float*)alloc((size_t)N_NODES * D * sizeof(float));
    float* h2      = (float*)alloc((size_t)N_NODES * D * sizeof(float));
    // zeroable: bm0|bm1|bm2, cnt3b, indeg, n0, n1
    const int ZN   = 3 * BMW + 3 * NBLK + N_NODES + 64;
    int*   zbase   = (int*)alloc((size_t)ZN * sizeof(int));
    unsigned* bm0  = (unsigned*)zbase;
    unsigned* bm1  = (unsigned*)(zbase + BMW);
    unsigned* bm2  = (unsigned*)(zbase + 2 * BMW);
    int* cnt3b = zbase + 3 * BMW;
    int* indeg = zbase + 3 * BMW + 3 * NBLK;
    int* n0    = indeg + N_NODES;
    int* n1    = n0 + 1;
    (void)ws_size; (void)in_sizes; (void)n_in; (void)out_size;

    const int EB = (N_EDGES + 255) / 256;   // 5120

    zero_f4   <<<(N_NODES * D / 4 + 255) / 256, 256, 0, stream>>>((float4*)agg, N_NODES * D / 4);
    zero_ints <<<(ZN + 255) / 256, 256, 0, stream>>>(zbase, ZN);
    find_first<<<NB, 256, 0, stream>>>(batch, fidx);

    // masks (bitmasks): bm2 = outputs; bm1 = bm2 ∪ src(dst∈bm2); bm0 = bm1 ∪ src(dst∈bm1)
    mark_set_bm <<<1, NG, 0, stream>>>(fidx, bm2, bm1);
    mark_srcs_bm<<<EB, 256, 0, stream>>>(src, dst, bm2, bm1, (const unsigned*)nullptr);
    mark_srcs_bm<<<EB, 256, 0, stream>>>(src, dst, bm1, bm0, bm1);   // incl. OR-copy bm1->bm0
    compact2_bm <<<NB, 256, 0, stream>>>(bm0, bm1, list0, list1, n0, n1);

    // CSR build + exact in-degree (properly parallelized: 320 WGs)
    hist_cnt  <<<HWGS, 256, 0, stream>>>(src, dst, bm0, bm1, bm2, cnt3b, indeg);
    scan1280  <<<3, 256, 0, stream>>>(cnt3b, rp3b, cur3b);
    bucket3   <<<HWGS, 256, 0, stream>>>(src, dst, bm0, bm1, bm2, cur3b, esp0, esp1, esp2);

    // layer 0: push dst∈m0, finish on m0 list
    sage_push      <<<NBLK, 256, 0, stream>>>(x, rp3b, esp0, agg);
    sage_finish_sel<<<NBLK, 256, 0, stream>>>(x, agg, indeg, list0, n0,
                                              h1, Wl0, bl0, Wr0, 1);
    // layer 1: push dst∈m1, finish on m1 list
    sage_push      <<<NBLK, 256, 0, stream>>>(h1, rp3b + RPW, esp1, agg);
    sage_finish_sel<<<NBLK, 256, 0, stream>>>(h1, agg, indeg, list1, n1,
                                              h2, Wl1, bl1, Wr1, 1);
    // layer 2: push dst∈m2, GEMM on the 256 output nodes
    sage_push      <<<NBLK, 256, 0, stream>>>(h2, rp3b + 2 * RPW, esp2, agg);
    final_gemm_sel <<<NG / TM, 256, 0, stream>>>(h2, agg, indeg, fidx, Wl2, bl2, Wr2, out);
}

// Round 10
// 493.959 us; speedup vs baseline: 4.1583x; 1.0561x over previous
//
#include <hip/hip_runtime.h>

#define N_NODES 81920
#define N_EDGES 1310720
#define NG 256
#define D 64
#define TM 64
#define SA 65            // LDS row stride: 2-way bank alias max (free)
#define NB 320           // 256-thread node blocks covering N_NODES
#define NBLK 1280        // src blocks of 64 nodes
#define BMW 2560         // bitmask words (81920/32)
#define HCHUNK 4096      // edges per build workgroup (NB*HCHUNK == N_EDGES)
#define CAP0 1280        // slab capacities per src block (mean 576, sigma 24)
#define CAP1 256         // (mean ~54, sigma ~7)
#define CAP2 64          // (mean ~3)

__device__ __forceinline__ bool tb(const unsigned* bm, int i) {
    return (bm[i >> 5] >> (i & 31)) & 1u;
}

// ---------------- init: zero agg/bitmasks/indeg/counters, init slab cursors ----------

__global__ __launch_bounds__(256) void init_ws(float4* __restrict__ agg4,
                                               unsigned* __restrict__ bms,   // 3*BMW
                                               int* __restrict__ indeg,
                                               int* __restrict__ n01,
                                               int* __restrict__ cur0,
                                               int* __restrict__ cur1,
                                               int* __restrict__ cur2) {
    int t = blockIdx.x * 256 + threadIdx.x;          // grid 1280 -> 327680 threads
    float4 z = make_float4(0.f, 0.f, 0.f, 0.f);
    #pragma unroll
    for (int r = 0; r < 4; ++r) agg4[t + r * (NBLK * 256)] = z;   // 1.31M float4
    if (t < 3 * BMW) bms[t] = 0u;
    if (t < N_NODES) indeg[t] = 0;
    if (t < 2) n01[t] = 0;
    if (t < NBLK) {
        cur0[t] = t * CAP0;
        cur1[t] = t * CAP1;
        cur2[t] = t * CAP2;
    }
}

// ---------------- find first node of each graph + seed bm2/bm1 ----------------

__global__ void ff_mark(const int* __restrict__ batch, int* __restrict__ fidx,
                        unsigned* __restrict__ bm2, unsigned* __restrict__ bm1) {
    int i = blockIdx.x * 256 + threadIdx.x;          // grid NB
    int b = batch[i];
    if (i == 0 || batch[i - 1] != b) {
        fidx[b] = i;
        unsigned bit = 1u << (i & 31);
        atomicOr(&bm2[i >> 5], bit);
        atomicOr(&bm1[i >> 5], bit);
    }
}

// mark srcs of edges with dst-bit in bmD into bmS; optional OR-copy orsrc -> bmS
__global__ void mark_srcs_bm(const int* __restrict__ src, const int* __restrict__ dst,
                             const unsigned* __restrict__ bmD, unsigned* __restrict__ bmS,
                             const unsigned* __restrict__ orsrc) {
    if (orsrc && blockIdx.x == 0) {
        for (int w = threadIdx.x; w < BMW; w += 256)
            if (orsrc[w]) atomicOr(&bmS[w], orsrc[w]);
    }
    int e = blockIdx.x * 256 + threadIdx.x;
    if (e < N_EDGES && tb(bmD, dst[e])) {
        int s = src[e];
        atomicOr(&bmS[s >> 5], 1u << (s & 31));
    }
}

// ---------------- build: compact lists + bucket 3 layers into fixed slabs + indeg ----
// No count pass, no scan: per-WG LDS histogram -> bulk reserve from absolute cursors.

__global__ __launch_bounds__(256) void build(const int* __restrict__ src,
                                             const int* __restrict__ dst,
                                             const unsigned* __restrict__ bm0,
                                             const unsigned* __restrict__ bm1,
                                             const unsigned* __restrict__ bm2,
                                             int* __restrict__ cur0,
                                             int* __restrict__ cur1,
                                             int* __restrict__ cur2,
                                             int* __restrict__ esp0,
                                             int* __restrict__ esp1,
                                             int* __restrict__ esp2,
                                             int* __restrict__ indeg,
                                             int* __restrict__ list0,
                                             int* __restrict__ list1,
                                             int* __restrict__ n0,
                                             int* __restrict__ n1) {
    __shared__ int h0[NBLK], h1s[NBLK], h2s[NBLK];
    const int tid = threadIdx.x;
    const int e0  = blockIdx.x * HCHUNK;             // grid NB (320)

    for (int i = tid; i < NBLK; i += 256) { h0[i] = 0; h1s[i] = 0; h2s[i] = 0; }

    // node-list compaction for this WG's 256-node chunk (independent of LDS hists)
    {
        int i = blockIdx.x * 256 + tid;
        int lane = tid & 63;
        bool p0 = tb(bm0, i);
        bool p1 = tb(bm1, i);
        unsigned long long b0 = __ballot(p0);
        int lt = __popcll(b0 & ((1ull << lane) - 1));
        int base = 0;
        if (lane == 0 && b0) base = atomicAdd(n0, __popcll(b0));
        base = __shfl(base, 0);
        if (p0) list0[base + lt] = i;
        unsigned long long b1 = __ballot(p1);
        lt = __popcll(b1 & ((1ull << lane) - 1));
        base = 0;
        if (lane == 0 && b1) base = atomicAdd(n1, __popcll(b1));
        base = __shfl(base, 0);
        if (p1) list1[base + lt] = i;
    }
    __syncthreads();

    // pass 1: count into LDS histograms
    for (int e = e0 + tid; e < e0 + HCHUNK; e += 256) {
        int d = dst[e];
        if (tb(bm0, d)) {
            int sb = src[e] >> 6;
            atomicAdd(&h0[sb], 1);
            if (tb(bm1, d)) {
                atomicAdd(&h1s[sb], 1);
                if (tb(bm2, d)) atomicAdd(&h2s[sb], 1);
            }
        }
    }
    __syncthreads();

    // bulk-reserve slab chunks (absolute offsets)
    for (int i = tid; i < NBLK; i += 256) {
        int c = h0[i];  h0[i]  = c ? atomicAdd(&cur0[i], c) : 0;
        c = h1s[i];     h1s[i] = c ? atomicAdd(&cur1[i], c) : 0;
        c = h2s[i];     h2s[i] = c ? atomicAdd(&cur2[i], c) : 0;
    }
    __syncthreads();

    // pass 2: place + in-degree (for d in m0 ALL in-edges pass -> exact divisor)
    for (int e = e0 + tid; e < e0 + HCHUNK; e += 256) {
        int d = dst[e];
        if (tb(bm0, d)) {
            int s  = src[e];
            int sb = s >> 6;
            int pk = (d << 6) | (s & 63);
            atomicAdd(&indeg[d], 1);                  // fire-and-forget
            int pos = atomicAdd(&h0[sb], 1);          // LDS cursor
            if (pos < sb * CAP0 + CAP0) esp0[pos] = pk;
            if (tb(bm1, d)) {
                pos = atomicAdd(&h1s[sb], 1);
                if (pos < sb * CAP1 + CAP1) esp1[pos] = pk;
                if (tb(bm2, d)) {
                    pos = atomicAdd(&h2s[sb], 1);
                    if (pos < sb * CAP2 + CAP2) esp2[pos] = pk;
                }
            }
        }
    }
}

// ---------------- push phase: LDS-staged rows + fire-and-forget scatter atomics ----

__global__ __launch_bounds__(256, 8) void sage_push(
    const float* __restrict__ hin, const int* __restrict__ cur,
    const int* __restrict__ esp, float* __restrict__ agg, int cap)
{
    __shared__ float Rs[TM * SA];     // this block's 64 src rows

    const int tid  = threadIdx.x;
    const int base = blockIdx.x * TM;
    const int lane = tid & 63;
    const int w    = tid >> 6;

    const int e0 = blockIdx.x * cap;
    const int e1 = min(cur[blockIdx.x], e0 + cap);
    if (e0 == e1) return;             // nothing to push from this block

    for (int idx = tid; idx < TM * D; idx += 256) {
        int m = idx >> 6, k = idx & 63;
        Rs[m * SA + k] = hin[(base << 6) + idx];   // coalesced stream
    }
    __syncthreads();

    const int chunk = ((e1 - e0) + 3) >> 2;
    int e = e0 + w * chunk;
    const int ee = min(e + chunk, e1);

    for (; e + 64 <= ee; e += 64) {
        int pv = esp[e + lane];                    // 64 edges, one coalesced load
        #pragma unroll
        for (int u = 0; u < 64; ++u) {
            int p = __shfl(pv, u);                 // broadcast edge u
            float v = Rs[(p & 63) * SA + lane];    // LDS row read, 2-way alias
            atomicAdd(&agg[(p & 0x7fffffc0) + lane], v);  // fire-and-forget f32 atomic
        }
    }
    for (; e < ee; ++e) {
        int p = esp[e];
        atomicAdd(&agg[(p & 0x7fffffc0) + lane], Rs[(p & 63) * SA + lane]);
    }
}

// ---------------- finish on a compacted node list: scale + dual fp32 GEMM + re-zero ----

__global__ __launch_bounds__(256, 4) void sage_finish_sel(
    const float* __restrict__ hin, float* __restrict__ agg,
    const int* __restrict__ indeg, const int* __restrict__ list,
    const int* __restrict__ pcount, float* __restrict__ hout,
    const float* __restrict__ Wl, const float* __restrict__ bl,
    const float* __restrict__ Wr, int relu)
{
    __shared__ float As[TM * SA];
    __shared__ float Xs[TM * SA];
    __shared__ float invs[TM];
    __shared__ int   nid[TM];

    const int cntv = *pcount;
    const int base = blockIdx.x * TM;
    if (base >= cntv) return;

    const int tid = threadIdx.x;
    if (tid < TM) {
        int n = (base + tid < cntv) ? list[base + tid] : -1;
        nid[tid]  = n;
        invs[tid] = (n >= 0) ? 1.0f / (float)max(indeg[n], 1) : 0.f;
    }
    __syncthreads();
    for (int idx = tid; idx < TM * D; idx += 256) {
        int m = idx >> 6, k = idx & 63;
        int n = nid[m];
        if (n >= 0) {
            As[m * SA + k] = agg[n * D + k] * invs[m];
            Xs[m * SA + k] = hin[n * D + k];
            agg[n * D + k] = 0.0f;                 // re-zero for the next push phase
        } else {
            As[m * SA + k] = 0.f;
            Xs[m * SA + k] = 0.f;
        }
    }
    __syncthreads();

    const int j0 = (tid & 15) << 2;
    const int m0 = (tid >> 4) << 2;
    float o[4][4];
    float4 b4 = *(const float4*)&bl[j0];
    #pragma unroll
    for (int mi = 0; mi < 4; ++mi) {
        o[mi][0] = b4.x; o[mi][1] = b4.y; o[mi][2] = b4.z; o[mi][3] = b4.w;
    }
    #pragma unroll 8
    for (int k = 0; k < D; ++k) {
        float4 wl = *(const float4*)&Wl[(k << 6) + j0];   // global, L1-resident broadcast
        float4 wr = *(const float4*)&Wr[(k << 6) + j0];
        #pragma unroll
        for (int mi = 0; mi < 4; ++mi) {
            float a = As[(m0 + mi) * SA + k];
            float x = Xs[(m0 + mi) * SA + k];
            o[mi][0] += a * wl.x + x * wr.x;
            o[mi][1] += a * wl.y + x * wr.y;
            o[mi][2] += a * wl.z + x * wr.z;
            o[mi][3] += a * wl.w + x * wr.w;
        }
    }
    #pragma unroll
    for (int mi = 0; mi < 4; ++mi) {
        int n = nid[m0 + mi];
        if (n >= 0) {
            float4 r = make_float4(o[mi][0], o[mi][1], o[mi][2], o[mi][3]);
            if (relu) {
                r.x = fmaxf(r.x, 0.f); r.y = fmaxf(r.y, 0.f);
                r.z = fmaxf(r.z, 0.f); r.w = fmaxf(r.w, 0.f);
            }
            *(float4*)&hout[n * D + j0] = r;
        }
    }
}

// ---------------- final layer GEMM on the 256 selected nodes ----------------

__global__ __launch_bounds__(256, 3) void final_gemm_sel(
    const float* __restrict__ hin, const float* __restrict__ agg,
    const int* __restrict__ indeg, const int* __restrict__ fidx,
    const float* __restrict__ Wl, const float* __restrict__ bl,
    const float* __restrict__ Wr, float* __restrict__ out)
{
    __shared__ float As[TM * SA];
    __shared__ float Xs[TM * SA];
    __shared__ int   nid[TM];
    __shared__ float invs[TM];

    const int tid  = threadIdx.x;
    const int base = blockIdx.x * TM;

    if (tid < TM) {
        int n = fidx[base + tid];
        nid[tid]  = n;
        invs[tid] = 1.0f / (float)max(indeg[n], 1);
    }
    __syncthreads();
    for (int idx = tid; idx < TM * D; idx += 256) {
        int m = idx >> 6, k = idx & 63;
        int n = nid[m];
        As[m * SA + k] = agg[n * D + k] * invs[m];
        Xs[m * SA + k] = hin[n * D + k];
    }
    __syncthreads();

    const int j0 = (tid & 15) << 2;
    const int m0 = (tid >> 4) << 2;
    float o[4][4];
    float4 b4 = *(const float4*)&bl[j0];
    #pragma unroll
    for (int mi = 0; mi < 4; ++mi) {
        o[mi][0] = b4.x; o[mi][1] = b4.y; o[mi][2] = b4.z; o[mi][3] = b4.w;
    }
    #pragma unroll 8
    for (int k = 0; k < D; ++k) {
        float4 wl = *(const float4*)&Wl[(k << 6) + j0];
        float4 wr = *(const float4*)&Wr[(k << 6) + j0];
        #pragma unroll
        for (int mi = 0; mi < 4; ++mi) {
            float a = As[(m0 + mi) * SA + k];
            float x = Xs[(m0 + mi) * SA + k];
            o[mi][0] += a * wl.x + x * wr.x;
            o[mi][1] += a * wl.y + x * wr.y;
            o[mi][2] += a * wl.z + x * wr.z;
            o[mi][3] += a * wl.w + x * wr.w;
        }
    }
    #pragma unroll
    for (int mi = 0; mi < 4; ++mi) {
        float4 r = make_float4(o[mi][0], o[mi][1], o[mi][2], o[mi][3]);
        *(float4*)&out[(base + m0 + mi) * D + j0] = r;
    }
}

// ---------------- launch ----------------

extern "C" void kernel_launch(void* const* d_in, const int* in_sizes, int n_in,
                              void* d_out, int out_size, void* d_ws, size_t ws_size,
                              hipStream_t stream)
{
    const float* x     = (const float*)d_in[0];
    const int*   ei    = (const int*)d_in[1];
    const int*   batch = (const int*)d_in[2];
    const float* Wl0 = (const float*)d_in[3];
    const float* bl0 = (const float*)d_in[4];
    const float* Wr0 = (const float*)d_in[5];
    const float* Wl1 = (const float*)d_in[6];
    const float* bl1 = (const float*)d_in[7];
    const float* Wr1 = (const float*)d_in[8];
    const float* Wl2 = (const float*)d_in[9];
    const float* bl2 = (const float*)d_in[10];
    const float* Wr2 = (const float*)d_in[11];
    float* out = (float*)d_out;

    const int* src = ei;             // edge_index[0]
    const int* dst = ei + N_EDGES;   // edge_index[1]

    char* ws = (char*)d_ws;
    size_t off = 0;
    auto alloc = [&](size_t bytes) -> void* {
        void* p = ws + off;
        off = (off + bytes + 255) & ~(size_t)255;
        return p;
    };
    int*   cur0    = (int*)alloc(NBLK * sizeof(int));
    int*   cur1    = (int*)alloc(NBLK * sizeof(int));
    int*   cur2    = (int*)alloc(NBLK * sizeof(int));
    int*   fidx    = (int*)alloc(NG * sizeof(int));
    int*   list0   = (int*)alloc(N_NODES * sizeof(int));
    int*   list1   = (int*)alloc(N_NODES * sizeof(int));
    int*   esp0    = (int*)alloc((size_t)NBLK * CAP0 * sizeof(int));
    int*   esp1    = (int*)alloc((size_t)NBLK * CAP1 * sizeof(int));
    int*   esp2    = (int*)alloc((size_t)NBLK * CAP2 * sizeof(int));
    float* agg     = (float*)alloc((size_t)N_NODES * D * sizeof(float));
    float* h1      = (float*)alloc((size_t)N_NODES * D * sizeof(float));
    float* h2      = (float*)alloc((size_t)N_NODES * D * sizeof(float));
    unsigned* bms  = (unsigned*)alloc((size_t)3 * BMW * sizeof(unsigned));
    int*   indeg   = (int*)alloc(N_NODES * sizeof(int));
    int*   n01     = (int*)alloc(64 * sizeof(int));
    unsigned* bm0  = bms;
    unsigned* bm1  = bms + BMW;
    unsigned* bm2  = bms + 2 * BMW;
    int* n0 = n01;
    int* n1 = n01 + 1;
    (void)ws_size; (void)in_sizes; (void)n_in; (void)out_size;

    const int EB = (N_EDGES + 255) / 256;   // 5120

    // 1. init everything zeroable + slab cursors
    init_ws<<<NBLK, 256, 0, stream>>>((float4*)agg, bms, indeg, n01, cur0, cur1, cur2);
    // 2. graph firsts + seed bm2/bm1
    ff_mark<<<NB, 256, 0, stream>>>(batch, fidx, bm2, bm1);
    // 3-4. masks: bm1 |= src(dst in bm2); bm0 = bm1 | src(dst in bm1)
    mark_srcs_bm<<<EB, 256, 0, stream>>>(src, dst, bm2, bm1, (const unsigned*)nullptr);
    mark_srcs_bm<<<EB, 256, 0, stream>>>(src, dst, bm1, bm0, bm1);
    // 5. compact lists + bucket all three layers + indeg (no count pass, no scan)
    build<<<NB, 256, 0, stream>>>(src, dst, bm0, bm1, bm2, cur0, cur1, cur2,
                                  esp0, esp1, esp2, indeg, list0, list1, n0, n1);

    // 6-7. layer 0
    sage_push      <<<NBLK, 256, 0, stream>>>(x, cur0, esp0, agg, CAP0);
    sage_finish_sel<<<NBLK, 256, 0, stream>>>(x, agg, indeg, list0, n0,
                                              h1, Wl0, bl0, Wr0, 1);
    // 8-9. layer 1
    sage_push      <<<NBLK, 256, 0, stream>>>(h1, cur1, esp1, agg, CAP1);
    sage_finish_sel<<<NBLK, 256, 0, stream>>>(h1, agg, indeg, list1, n1,
                                              h2, Wl1, bl1, Wr1, 1);
    // 10-11. layer 2 + output GEMM
    sage_push      <<<NBLK, 256, 0, stream>>>(h2, cur2, esp2, agg, CAP2);
    final_gemm_sel <<<NG / TM, 256, 0, stream>>>(h2, agg, indeg, fidx, Wl2, bl2, Wr2, out);
}

// Round 11
// 410.437 us; speedup vs baseline: 5.0044x; 1.2035x over previous
//
#include <hip/hip_runtime.h>

#define N_NODES 81920
#define N_EDGES 1310720
#define NG 256
#define D 64
#define TM 64
#define SA 65            // f32 LDS row stride (finish/final GEMM tiles)
#define SB 33            // bf16x2 LDS row stride in push (2-way bank alias, free)
#define NB 320           // 256-thread node blocks covering N_NODES
#define NBLK 1280        // src blocks of 64 nodes
#define BMW 2560         // bitmask words (81920/32)
#define HCHUNK 4096      // edges per build workgroup (NB*HCHUNK == N_EDGES)
#define CAP0 1280        // slab capacities per src block (mean 576, sigma 24)
#define CAP1 256
#define CAP2 64

typedef __attribute__((ext_vector_type(2))) short sbf2;

__device__ __forceinline__ bool tb(const unsigned* bm, int i) {
    return (bm[i >> 5] >> (i & 31)) & 1u;
}
__device__ __forceinline__ unsigned bf16rne(float f) {
    unsigned u = __float_as_uint(f);
    return (u + 0x7fffu + ((u >> 16) & 1u)) >> 16;
}

// ---------------- init: zero aggb/bitmasks/indeg/counters, init slab cursors --------

__global__ __launch_bounds__(256) void init_ws(float4* __restrict__ aggb4,
                                               unsigned* __restrict__ bms,   // 3*BMW
                                               int* __restrict__ indeg,
                                               int* __restrict__ n01,
                                               int* __restrict__ cur0,
                                               int* __restrict__ cur1,
                                               int* __restrict__ cur2) {
    int t = blockIdx.x * 256 + threadIdx.x;          // grid 1280 -> 327680 threads
    float4 z = make_float4(0.f, 0.f, 0.f, 0.f);
    aggb4[t] = z;                                    // 655360 float4 = 10.5 MB bf16 agg
    aggb4[t + NBLK * 256] = z;
    if (t < 3 * BMW) bms[t] = 0u;
    if (t < N_NODES) indeg[t] = 0;
    if (t < 2) n01[t] = 0;
    if (t < NBLK) {
        cur0[t] = t * CAP0;
        cur1[t] = t * CAP1;
        cur2[t] = t * CAP2;
    }
}

// ---------------- graph firsts + seed bm2/bm1 + zero the 256 f32 agg rows ----------

__global__ void ff_mark(const int* __restrict__ batch, int* __restrict__ fidx,
                        unsigned* __restrict__ bm2, unsigned* __restrict__ bm1,
                        float* __restrict__ aggf) {
    int i = blockIdx.x * 256 + threadIdx.x;          // grid NB
    int b = batch[i];
    if (i == 0 || batch[i - 1] != b) {
        fidx[b] = i;
        unsigned bit = 1u << (i & 31);
        atomicOr(&bm2[i >> 5], bit);
        atomicOr(&bm1[i >> 5], bit);
        float4* r = (float4*)&aggf[i * D];           // zero this output row (layer-2 f32 agg)
        #pragma unroll
        for (int j = 0; j < 16; ++j) r[j] = make_float4(0.f, 0.f, 0.f, 0.f);
    }
}

// mark srcs of edges with dst-bit in bmD into bmS; optional OR-copy orsrc -> bmS
__global__ void mark_srcs_bm(const int* __restrict__ src, const int* __restrict__ dst,
                             const unsigned* __restrict__ bmD, unsigned* __restrict__ bmS,
                             const unsigned* __restrict__ orsrc) {
    if (orsrc && blockIdx.x == 0) {
        for (int w = threadIdx.x; w < BMW; w += 256)
            if (orsrc[w]) atomicOr(&bmS[w], orsrc[w]);
    }
    int e = blockIdx.x * 256 + threadIdx.x;
    if (e < N_EDGES && tb(bmD, dst[e])) {
        int s = src[e];
        atomicOr(&bmS[s >> 5], 1u << (s & 31));
    }
}

// ---------------- build: compact lists + bucket 3 layers into fixed slabs + indeg ----

__global__ __launch_bounds__(256) void build(const int* __restrict__ src,
                                             const int* __restrict__ dst,
                                             const unsigned* __restrict__ bm0,
                                             const unsigned* __restrict__ bm1,
                                             const unsigned* __restrict__ bm2,
                                             int* __restrict__ cur0,
                                             int* __restrict__ cur1,
                                             int* __restrict__ cur2,
                                             int* __restrict__ esp0,
                                             int* __restrict__ esp1,
                                             int* __restrict__ esp2,
                                             int* __restrict__ indeg,
                                             int* __restrict__ list0,
                                             int* __restrict__ list1,
                                             int* __restrict__ n0,
                                             int* __restrict__ n1) {
    __shared__ int h0[NBLK], h1s[NBLK], h2s[NBLK];
    const int tid = threadIdx.x;
    const int e0  = blockIdx.x * HCHUNK;             // grid NB (320)

    for (int i = tid; i < NBLK; i += 256) { h0[i] = 0; h1s[i] = 0; h2s[i] = 0; }

    // node-list compaction for this WG's 256-node chunk
    {
        int i = blockIdx.x * 256 + tid;
        int lane = tid & 63;
        bool p0 = tb(bm0, i);
        bool p1 = tb(bm1, i);
        unsigned long long b0 = __ballot(p0);
        int lt = __popcll(b0 & ((1ull << lane) - 1));
        int base = 0;
        if (lane == 0 && b0) base = atomicAdd(n0, __popcll(b0));
        base = __shfl(base, 0);
        if (p0) list0[base + lt] = i;
        unsigned long long b1 = __ballot(p1);
        lt = __popcll(b1 & ((1ull << lane) - 1));
        base = 0;
        if (lane == 0 && b1) base = atomicAdd(n1, __popcll(b1));
        base = __shfl(base, 0);
        if (p1) list1[base + lt] = i;
    }
    __syncthreads();

    // pass 1: count into LDS histograms
    for (int e = e0 + tid; e < e0 + HCHUNK; e += 256) {
        int d = dst[e];
        if (tb(bm0, d)) {
            int sb = src[e] >> 6;
            atomicAdd(&h0[sb], 1);
            if (tb(bm1, d)) {
                atomicAdd(&h1s[sb], 1);
                if (tb(bm2, d)) atomicAdd(&h2s[sb], 1);
            }
        }
    }
    __syncthreads();

    // bulk-reserve slab chunks (absolute offsets)
    for (int i = tid; i < NBLK; i += 256) {
        int c = h0[i];  h0[i]  = c ? atomicAdd(&cur0[i], c) : 0;
        c = h1s[i];     h1s[i] = c ? atomicAdd(&cur1[i], c) : 0;
        c = h2s[i];     h2s[i] = c ? atomicAdd(&cur2[i], c) : 0;
    }
    __syncthreads();

    // pass 2: place + in-degree (for d in m0 ALL in-edges pass -> exact divisor)
    for (int e = e0 + tid; e < e0 + HCHUNK; e += 256) {
        int d = dst[e];
        if (tb(bm0, d)) {
            int s  = src[e];
            int sb = s >> 6;
            int pk = (d << 6) | (s & 63);
            atomicAdd(&indeg[d], 1);                  // fire-and-forget
            int pos = atomicAdd(&h0[sb], 1);          // LDS cursor
            if (pos < sb * CAP0 + CAP0) esp0[pos] = pk;
            if (tb(bm1, d)) {
                pos = atomicAdd(&h1s[sb], 1);
                if (pos < sb * CAP1 + CAP1) esp1[pos] = pk;
                if (tb(bm2, d)) {
                    pos = atomicAdd(&h2s[sb], 1);
                    if (pos < sb * CAP2 + CAP2) esp2[pos] = pk;
                }
            }
        }
    }
}

// ---------------- push (bf16x2 pk atomics): 128 B/edge, 2 edges per wave-step ----

__global__ __launch_bounds__(256, 8) void sage_push_bf(
    const float* __restrict__ hin, const int* __restrict__ cur,
    const int* __restrict__ esp, unsigned* __restrict__ aggb, int cap)
{
    __shared__ unsigned Rs[TM * SB];  // 64 src rows, pre-packed bf16x2 (8.4 KB)

    const int tid  = threadIdx.x;
    const int base = blockIdx.x * TM;
    const int lane = tid & 63;
    const int w    = tid >> 6;
    const int l5   = lane & 31;       // feature pair index
    const int hi   = lane >> 5;       // 0 = even edge, 1 = odd edge

    const int e0 = blockIdx.x * cap;
    const int e1 = min(cur[blockIdx.x], e0 + cap);
    if (e0 == e1) return;

    for (int idx = tid; idx < TM * 32; idx += 256) {
        int m = idx >> 5, k = idx & 31;
        float2 v = *(const float2*)&hin[((base + m) << 6) + (k << 1)];
        Rs[m * SB + k] = bf16rne(v.x) | (bf16rne(v.y) << 16);
    }
    __syncthreads();

    const int chunk = ((e1 - e0) + 3) >> 2;
    int e = e0 + w * chunk;
    const int ee = min(e + chunk, e1);

    for (; e + 64 <= ee; e += 64) {
        int pv = esp[e + lane];                       // 64 edges, one coalesced load
        #pragma unroll
        for (int u = 0; u < 32; ++u) {                // 2 edges per step (half-wave each)
            int p = __shfl(pv, (u << 1) + hi);
            unsigned v = Rs[(p & 63) * SB + l5];      // ds_read_b32, 2-way alias
            __builtin_amdgcn_global_atomic_fadd_v2bf16(
                (sbf2*)&aggb[((p >> 6) << 5) + l5], *(sbf2*)&v);   // fire-and-forget pk
        }
    }
    for (; e < ee; ++e) {                             // tail: half-wave covers 64 features
        int p = esp[e];
        if (!hi) {
            unsigned v = Rs[(p & 63) * SB + l5];
            __builtin_amdgcn_global_atomic_fadd_v2bf16(
                (sbf2*)&aggb[((p >> 6) << 5) + l5], *(sbf2*)&v);
        }
    }
}

// ---------------- push (f32, exact): used for layer 2 into aggf ----------------

__global__ __launch_bounds__(256, 8) void sage_push_f32(
    const float* __restrict__ hin, const int* __restrict__ cur,
    const int* __restrict__ esp, float* __restrict__ agg, int cap)
{
    __shared__ float Rs[TM * SA];

    const int tid  = threadIdx.x;
    const int base = blockIdx.x * TM;
    const int lane = tid & 63;
    const int w    = tid >> 6;

    const int e0 = blockIdx.x * cap;
    const int e1 = min(cur[blockIdx.x], e0 + cap);
    if (e0 == e1) return;

    for (int idx = tid; idx < TM * D; idx += 256) {
        int m = idx >> 6, k = idx & 63;
        Rs[m * SA + k] = hin[(base << 6) + idx];
    }
    __syncthreads();

    const int chunk = ((e1 - e0) + 3) >> 2;
    int e = e0 + w * chunk;
    const int ee = min(e + chunk, e1);

    for (; e < ee; ++e) {
        int p = esp[e];
        atomicAdd(&agg[(p & 0x7fffffc0) + lane], Rs[(p & 63) * SA + lane]);
    }
}

// ---------------- finish on compacted list: unpack bf16 agg + dual fp32 GEMM --------

__global__ __launch_bounds__(256, 4) void sage_finish_sel(
    const float* __restrict__ hin, unsigned* __restrict__ aggb,
    const int* __restrict__ indeg, const int* __restrict__ list,
    const int* __restrict__ pcount, float* __restrict__ hout,
    const float* __restrict__ Wl, const float* __restrict__ bl,
    const float* __restrict__ Wr, int relu)
{
    __shared__ float As[TM * SA];
    __shared__ float Xs[TM * SA];
    __shared__ float invs[TM];
    __shared__ int   nid[TM];

    const int cntv = *pcount;
    const int base = blockIdx.x * TM;
    if (base >= cntv) return;

    const int tid = threadIdx.x;
    if (tid < TM) {
        int n = (base + tid < cntv) ? list[base + tid] : -1;
        nid[tid]  = n;
        invs[tid] = (n >= 0) ? 1.0f / (float)max(indeg[n], 1) : 0.f;
    }
    __syncthreads();
    for (int idx = tid; idx < TM * 32; idx += 256) {   // unpack bf16x2 agg + re-zero
        int m = idx >> 5, k2 = idx & 31;
        int n = nid[m];
        if (n >= 0) {
            unsigned v = aggb[(n << 5) + k2];
            As[m * SA + (k2 << 1)]     = __uint_as_float(v << 16) * invs[m];
            As[m * SA + (k2 << 1) + 1] = __uint_as_float(v & 0xffff0000u) * invs[m];
            aggb[(n << 5) + k2] = 0u;                  // re-zero for the next push
        } else {
            As[m * SA + (k2 << 1)]     = 0.f;
            As[m * SA + (k2 << 1) + 1] = 0.f;
        }
    }
    for (int idx = tid; idx < TM * D; idx += 256) {
        int m = idx >> 6, k = idx & 63;
        int n = nid[m];
        Xs[m * SA + k] = (n >= 0) ? hin[n * D + k] : 0.f;
    }
    __syncthreads();

    const int j0 = (tid & 15) << 2;
    const int m0 = (tid >> 4) << 2;
    float o[4][4];
    float4 b4 = *(const float4*)&bl[j0];
    #pragma unroll
    for (int mi = 0; mi < 4; ++mi) {
        o[mi][0] = b4.x; o[mi][1] = b4.y; o[mi][2] = b4.z; o[mi][3] = b4.w;
    }
    #pragma unroll 8
    for (int k = 0; k < D; ++k) {
        float4 wl = *(const float4*)&Wl[(k << 6) + j0];
        float4 wr = *(const float4*)&Wr[(k << 6) + j0];
        #pragma unroll
        for (int mi = 0; mi < 4; ++mi) {
            float a = As[(m0 + mi) * SA + k];
            float x = Xs[(m0 + mi) * SA + k];
            o[mi][0] += a * wl.x + x * wr.x;
            o[mi][1] += a * wl.y + x * wr.y;
            o[mi][2] += a * wl.z + x * wr.z;
            o[mi][3] += a * wl.w + x * wr.w;
        }
    }
    #pragma unroll
    for (int mi = 0; mi < 4; ++mi) {
        int n = nid[m0 + mi];
        if (n >= 0) {
            float4 r = make_float4(o[mi][0], o[mi][1], o[mi][2], o[mi][3]);
            if (relu) {
                r.x = fmaxf(r.x, 0.f); r.y = fmaxf(r.y, 0.f);
                r.z = fmaxf(r.z, 0.f); r.w = fmaxf(r.w, 0.f);
            }
            *(float4*)&hout[n * D + j0] = r;
        }
    }
}

// ---------------- final layer GEMM on the 256 selected nodes (exact f32 agg) --------

__global__ __launch_bounds__(256, 3) void final_gemm_sel(
    const float* __restrict__ hin, const float* __restrict__ agg,
    const int* __restrict__ indeg, const int* __restrict__ fidx,
    const float* __restrict__ Wl, const float* __restrict__ bl,
    const float* __restrict__ Wr, float* __restrict__ out)
{
    __shared__ float As[TM * SA];
    __shared__ float Xs[TM * SA];
    __shared__ int   nid[TM];
    __shared__ float invs[TM];

    const int tid  = threadIdx.x;
    const int base = blockIdx.x * TM;

    if (tid < TM) {
        int n = fidx[base + tid];
        nid[tid]  = n;
        invs[tid] = 1.0f / (float)max(indeg[n], 1);
    }
    __syncthreads();
    for (int idx = tid; idx < TM * D; idx += 256) {
        int m = idx >> 6, k = idx & 63;
        int n = nid[m];
        As[m * SA + k] = agg[n * D + k] * invs[m];
        Xs[m * SA + k] = hin[n * D + k];
    }
    __syncthreads();

    const int j0 = (tid & 15) << 2;
    const int m0 = (tid >> 4) << 2;
    float o[4][4];
    float4 b4 = *(const float4*)&bl[j0];
    #pragma unroll
    for (int mi = 0; mi < 4; ++mi) {
        o[mi][0] = b4.x; o[mi][1] = b4.y; o[mi][2] = b4.z; o[mi][3] = b4.w;
    }
    #pragma unroll 8
    for (int k = 0; k < D; ++k) {
        float4 wl = *(const float4*)&Wl[(k << 6) + j0];
        float4 wr = *(const float4*)&Wr[(k << 6) + j0];
        #pragma unroll
        for (int mi = 0; mi < 4; ++mi) {
            float a = As[(m0 + mi) * SA + k];
            float x = Xs[(m0 + mi) * SA + k];
            o[mi][0] += a * wl.x + x * wr.x;
            o[mi][1] += a * wl.y + x * wr.y;
            o[mi][2] += a * wl.z + x * wr.z;
            o[mi][3] += a * wl.w + x * wr.w;
        }
    }
    #pragma unroll
    for (int mi = 0; mi < 4; ++mi) {
        float4 r = make_float4(o[mi][0], o[mi][1], o[mi][2], o[mi][3]);
        *(float4*)&out[(base + m0 + mi) * D + j0] = r;
    }
}

// ---------------- launch ----------------

extern "C" void kernel_launch(void* const* d_in, const int* in_sizes, int n_in,
                              void* d_out, int out_size, void* d_ws, size_t ws_size,
                              hipStream_t stream)
{
    const float* x     = (const float*)d_in[0];
    const int*   ei    = (const int*)d_in[1];
    const int*   batch = (const int*)d_in[2];
    const float* Wl0 = (const float*)d_in[3];
    const float* bl0 = (const float*)d_in[4];
    const float* Wr0 = (const float*)d_in[5];
    const float* Wl1 = (const float*)d_in[6];
    const float* bl1 = (const float*)d_in[7];
    const float* Wr1 = (const float*)d_in[8];
    const float* Wl2 = (const float*)d_in[9];
    const float* bl2 = (const float*)d_in[10];
    const float* Wr2 = (const float*)d_in[11];
    float* out = (float*)d_out;

    const int* src = ei;             // edge_index[0]
    const int* dst = ei + N_EDGES;   // edge_index[1]

    char* ws = (char*)d_ws;
    size_t off = 0;
    auto alloc = [&](size_t bytes) -> void* {
        void* p = ws + off;
        off = (off + bytes + 255) & ~(size_t)255;
        return p;
    };
    int*      cur0  = (int*)alloc(NBLK * sizeof(int));
    int*      cur1  = (int*)alloc(NBLK * sizeof(int));
    int*      cur2  = (int*)alloc(NBLK * sizeof(int));
    int*      fidx  = (int*)alloc(NG * sizeof(int));
    int*      list0 = (int*)alloc(N_NODES * sizeof(int));
    int*      list1 = (int*)alloc(N_NODES * sizeof(int));
    int*      esp0  = (int*)alloc((size_t)NBLK * CAP0 * sizeof(int));
    int*      esp1  = (int*)alloc((size_t)NBLK * CAP1 * sizeof(int));
    int*      esp2  = (int*)alloc((size_t)NBLK * CAP2 * sizeof(int));
    unsigned* aggb  = (unsigned*)alloc((size_t)N_NODES * 32 * sizeof(unsigned)); // bf16x2
    float*    aggf  = (float*)alloc((size_t)N_NODES * D * sizeof(float));        // layer-2 exact
    float*    h1    = (float*)alloc((size_t)N_NODES * D * sizeof(float));
    float*    h2    = (float*)alloc((size_t)N_NODES * D * sizeof(float));
    unsigned* bms   = (unsigned*)alloc((size_t)3 * BMW * sizeof(unsigned));
    int*      indeg = (int*)alloc(N_NODES * sizeof(int));
    int*      n01   = (int*)alloc(64 * sizeof(int));
    unsigned* bm0 = bms;
    unsigned* bm1 = bms + BMW;
    unsigned* bm2 = bms + 2 * BMW;
    int* n0 = n01;
    int* n1 = n01 + 1;
    (void)ws_size; (void)in_sizes; (void)n_in; (void)out_size;

    const int EB = (N_EDGES + 255) / 256;   // 5120

    init_ws<<<NBLK, 256, 0, stream>>>((float4*)aggb, bms, indeg, n01, cur0, cur1, cur2);
    ff_mark<<<NB, 256, 0, stream>>>(batch, fidx, bm2, bm1, aggf);
    mark_srcs_bm<<<EB, 256, 0, stream>>>(src, dst, bm2, bm1, (const unsigned*)nullptr);
    mark_srcs_bm<<<EB, 256, 0, stream>>>(src, dst, bm1, bm0, bm1);
    build<<<NB, 256, 0, stream>>>(src, dst, bm0, bm1, bm2, cur0, cur1, cur2,
                                  esp0, esp1, esp2, indeg, list0, list1, n0, n1);

    // layer 0 (bf16 pk aggregation)
    sage_push_bf   <<<NBLK, 256, 0, stream>>>(x, cur0, esp0, aggb, CAP0);
    sage_finish_sel<<<NBLK, 256, 0, stream>>>(x, aggb, indeg, list0, n0,
                                              h1, Wl0, bl0, Wr0, 1);
    // layer 1 (bf16 pk aggregation)
    sage_push_bf   <<<NBLK, 256, 0, stream>>>(h1, cur1, esp1, aggb, CAP1);
    sage_finish_sel<<<NBLK, 256, 0, stream>>>(h1, aggb, indeg, list1, n1,
                                              h2, Wl1, bl1, Wr1, 1);
    // layer 2 (exact f32 aggregation into the 256 output rows) + output GEMM
    sage_push_f32  <<<NBLK, 256, 0, stream>>>(h2, cur2, esp2, aggf, CAP2);
    final_gemm_sel <<<NG / TM, 256, 0, stream>>>(h2, aggf, indeg, fidx, Wl2, bl2, Wr2, out);
}

// Round 12
// 404.354 us; speedup vs baseline: 5.0797x; 1.0150x over previous
//
#include <hip/hip_runtime.h>

#define N_NODES 81920
#define N_EDGES 1310720
#define NG 256
#define D 64
#define TM 64
#define SA 65            // f32 LDS row stride (GEMM tiles)
#define SB 33            // bf16x2 LDS row stride in push (2-way bank alias, free)
#define NB 320           // 256-thread node blocks covering N_NODES
#define NBLK 1280        // src blocks of 64 nodes
#define BMW 2560         // bitmask words (81920/32)
#define HCHUNK 4096      // edges per build workgroup (NB*HCHUNK == N_EDGES)
#define EPT 16           // edges per thread in build (HCHUNK/256)
#define CAP0 1280        // slab capacities per src block (mean 576, sigma 24)
#define CAP1 256
#define CAP2 64

typedef __attribute__((ext_vector_type(2))) short sbf2;

__device__ __forceinline__ bool tb(const unsigned* bm, int i) {
    return (bm[i >> 5] >> (i & 31)) & 1u;
}
__device__ __forceinline__ unsigned bf16rne(float f) {
    unsigned u = __float_as_uint(f);
    return (u + 0x7fffu + ((u >> 16) & 1u)) >> 16;
}

// ---------------- init: zero aggb/bitmasks/indeg/counters, init slab cursors --------

__global__ __launch_bounds__(256) void init_ws(float4* __restrict__ aggb4,
                                               unsigned* __restrict__ bms,   // 3*BMW
                                               int* __restrict__ indeg,
                                               int* __restrict__ n01,
                                               int* __restrict__ cur0,
                                               int* __restrict__ cur1,
                                               int* __restrict__ cur2) {
    int t = blockIdx.x * 256 + threadIdx.x;          // grid 1280 -> 327680 threads
    float4 z = make_float4(0.f, 0.f, 0.f, 0.f);
    aggb4[t] = z;                                    // 10.5 MB bf16x2 agg
    aggb4[t + NBLK * 256] = z;
    if (t < 3 * BMW) bms[t] = 0u;
    if (t < N_NODES) indeg[t] = 0;
    if (t < 2) n01[t] = 0;
    if (t < NBLK) {
        cur0[t] = t * CAP0;
        cur1[t] = t * CAP1;
        cur2[t] = t * CAP2;
    }
}

// ---------------- graph firsts + seed bm2/bm1 + zero the 256 f32 agg rows ----------

__global__ void ff_mark(const int* __restrict__ batch, int* __restrict__ fidx,
                        unsigned* __restrict__ bm2, unsigned* __restrict__ bm1,
                        float* __restrict__ aggf) {
    int i = blockIdx.x * 256 + threadIdx.x;          // grid NB
    int b = batch[i];
    if (i == 0 || batch[i - 1] != b) {
        fidx[b] = i;
        unsigned bit = 1u << (i & 31);
        atomicOr(&bm2[i >> 5], bit);
        atomicOr(&bm1[i >> 5], bit);
        float4* r = (float4*)&aggf[i * D];           // zero this output row (layer-2 agg)
        #pragma unroll
        for (int j = 0; j < 16; ++j) r[j] = make_float4(0.f, 0.f, 0.f, 0.f);
    }
}

// mark srcs of edges with dst-bit in bmD into bmS; optional OR-copy orsrc -> bmS
__global__ void mark_srcs_bm(const int* __restrict__ src, const int* __restrict__ dst,
                             const unsigned* __restrict__ bmD, unsigned* __restrict__ bmS,
                             const unsigned* __restrict__ orsrc) {
    if (orsrc && blockIdx.x == 0) {
        for (int w = threadIdx.x; w < BMW; w += 256)
            if (orsrc[w]) atomicOr(&bmS[w], orsrc[w]);
    }
    int e = blockIdx.x * 256 + threadIdx.x;
    if (e < N_EDGES && tb(bmD, dst[e])) {
        int s = src[e];
        atomicOr(&bmS[s >> 5], 1u << (s & 31));
    }
}

// ---------------- build: ONE edge stream, register-carried ranks, slab bucketing ----
// Layer 0 (93% of masked edges): LDS histogram + bulk reserve + register placement.
// Layers 1/2 (rare): direct global cursor atomics. + indeg + list1 compaction.

__global__ __launch_bounds__(256) void build(const int* __restrict__ src,
                                             const int* __restrict__ dst,
                                             const unsigned* __restrict__ bm0,
                                             const unsigned* __restrict__ bm1,
                                             const unsigned* __restrict__ bm2,
                                             int* __restrict__ cur0,
                                             int* __restrict__ cur1,
                                             int* __restrict__ cur2,
                                             int* __restrict__ esp0,
                                             int* __restrict__ esp1,
                                             int* __restrict__ esp2,
                                             int* __restrict__ indeg,
                                             int* __restrict__ list1,
                                             int* __restrict__ n1) {
    __shared__ int h0[NBLK];      // per-src-block count, then reused as-is
    __shared__ int b0[NBLK];      // reserved base per src block
    const int tid = threadIdx.x;
    const int e0  = blockIdx.x * HCHUNK;             // grid NB (320)

    for (int i = tid; i < NBLK; i += 256) h0[i] = 0;

    // list1 compaction for this WG's 256-node chunk (independent)
    {
        int i = blockIdx.x * 256 + tid;
        int lane = tid & 63;
        bool p1 = tb(bm1, i);
        unsigned long long b1 = __ballot(p1);
        int lt = __popcll(b1 & ((1ull << lane) - 1));
        int base = 0;
        if (lane == 0 && b1) base = atomicAdd(n1, __popcll(b1));
        base = __shfl(base, 0);
        if (p1) list1[base + lt] = i;
    }
    __syncthreads();

    int pk_r[EPT];
    int sb_r[EPT];
    int rk_r[EPT];

    // pass A: stream edges once; count L0 in LDS, carry ranks in registers;
    // place rare L1/L2 directly; indeg fire-and-forget
    #pragma unroll
    for (int j = 0; j < EPT; ++j) {
        int e = e0 + j * 256 + tid;                  // coalesced
        int d = dst[e];
        sb_r[j] = -1;
        if (tb(bm0, d)) {
            int s  = src[e];
            int sb = s >> 6;
            int pk = (d << 6) | (s & 63);
            pk_r[j] = pk;
            sb_r[j] = sb;
            rk_r[j] = atomicAdd(&h0[sb], 1);         // LDS
            atomicAdd(&indeg[d], 1);                 // global fire-and-forget
            if (tb(bm1, d)) {
                int p1 = atomicAdd(&cur1[sb], 1);    // rare (9%)
                if (p1 < sb * CAP1 + CAP1) esp1[p1] = pk;
                if (tb(bm2, d)) {
                    int p2 = atomicAdd(&cur2[sb], 1); // very rare (0.7%)
                    if (p2 < sb * CAP2 + CAP2) esp2[p2] = pk;
                }
            }
        }
    }
    __syncthreads();

    // bulk-reserve layer-0 slab chunks
    for (int i = tid; i < NBLK; i += 256) {
        int c = h0[i];
        b0[i] = c ? atomicAdd(&cur0[i], c) : 0;
    }
    __syncthreads();

    // pass B: place layer-0 edges from registers (no re-stream, no second LDS atomic)
    #pragma unroll
    for (int j = 0; j < EPT; ++j) {
        int sb = sb_r[j];
        if (sb >= 0) {
            int pos = b0[sb] + rk_r[j];
            if (pos < sb * CAP0 + CAP0) esp0[pos] = pk_r[j];
        }
    }
}

// ---------------- push (bf16x2 pk atomics): 128 B/edge, 2 edges per wave-step ----

__global__ __launch_bounds__(256, 8) void sage_push_bf(
    const float* __restrict__ hin, const int* __restrict__ cur,
    const int* __restrict__ esp, unsigned* __restrict__ aggb, int cap)
{
    __shared__ unsigned Rs[TM * SB];  // 64 src rows, pre-packed bf16x2

    const int tid  = threadIdx.x;
    const int base = blockIdx.x * TM;
    const int lane = tid & 63;
    const int w    = tid >> 6;
    const int l5   = lane & 31;
    const int hi   = lane >> 5;

    const int e0 = blockIdx.x * cap;
    const int e1 = min(cur[blockIdx.x], e0 + cap);
    if (e0 == e1) return;

    for (int idx = tid; idx < TM * 32; idx += 256) {
        int m = idx >> 5, k = idx & 31;
        float2 v = *(const float2*)&hin[((base + m) << 6) + (k << 1)];
        Rs[m * SB + k] = bf16rne(v.x) | (bf16rne(v.y) << 16);
    }
    __syncthreads();

    const int chunk = ((e1 - e0) + 3) >> 2;
    int e = e0 + w * chunk;
    const int ee = min(e + chunk, e1);

    for (; e + 64 <= ee; e += 64) {
        int pv = esp[e + lane];
        #pragma unroll
        for (int u = 0; u < 32; ++u) {
            int p = __shfl(pv, (u << 1) + hi);
            unsigned v = Rs[(p & 63) * SB + l5];
            __builtin_amdgcn_global_atomic_fadd_v2bf16(
                (sbf2*)&aggb[((p >> 6) << 5) + l5], *(sbf2*)&v);
        }
    }
    for (; e < ee; ++e) {
        int p = esp[e];
        if (!hi) {
            unsigned v = Rs[(p & 63) * SB + l5];
            __builtin_amdgcn_global_atomic_fadd_v2bf16(
                (sbf2*)&aggb[((p >> 6) << 5) + l5], *(sbf2*)&v);
        }
    }
}

// ---------------- push (f32, exact): layer 2 into aggf ----------------

__global__ __launch_bounds__(256, 8) void sage_push_f32(
    const float* __restrict__ hin, const int* __restrict__ cur,
    const int* __restrict__ esp, float* __restrict__ agg, int cap)
{
    __shared__ float Rs[TM * SA];

    const int tid  = threadIdx.x;
    const int base = blockIdx.x * TM;
    const int lane = tid & 63;
    const int w    = tid >> 6;

    const int e0 = blockIdx.x * cap;
    const int e1 = min(cur[blockIdx.x], e0 + cap);
    if (e0 == e1) return;

    for (int idx = tid; idx < TM * D; idx += 256) {
        int m = idx >> 6, k = idx & 63;
        Rs[m * SA + k] = hin[(base << 6) + idx];
    }
    __syncthreads();

    const int chunk = ((e1 - e0) + 3) >> 2;
    int e = e0 + w * chunk;
    const int ee = min(e + chunk, e1);

    for (; e < ee; ++e) {
        int p = esp[e];
        atomicAdd(&agg[(p & 0x7fffffc0) + lane], Rs[(p & 63) * SA + lane]);
    }
}

// ---------------- dense finish (layer 0): all nodes, fully coalesced ----------------

__global__ __launch_bounds__(256, 4) void sage_finish_dense(
    const float* __restrict__ hin, unsigned* __restrict__ aggb,
    const int* __restrict__ indeg, float* __restrict__ hout,
    const float* __restrict__ Wl, const float* __restrict__ bl,
    const float* __restrict__ Wr)
{
    __shared__ float As[TM * SA];
    __shared__ float Xs[TM * SA];
    __shared__ float invs[TM];

    const int tid  = threadIdx.x;
    const int base = blockIdx.x * TM;                // grid NBLK

    if (tid < TM) invs[tid] = 1.0f / (float)max(indeg[base + tid], 1);
    for (int idx = tid; idx < TM * 32; idx += 256) { // unpack bf16x2 agg + re-zero
        int m = idx >> 5, k2 = idx & 31;
        unsigned v = aggb[(base << 5) + idx];
        As[m * SA + (k2 << 1)]     = __uint_as_float(v << 16);
        As[m * SA + (k2 << 1) + 1] = __uint_as_float(v & 0xffff0000u);
        aggb[(base << 5) + idx] = 0u;                // re-zero for layer-1 push
    }
    for (int idx = tid; idx < TM * D; idx += 256) {
        int m = idx >> 6, k = idx & 63;
        Xs[m * SA + k] = hin[(base << 6) + idx];     // coalesced stream
    }
    __syncthreads();
    for (int idx = tid; idx < TM * D; idx += 256) {
        int m = idx >> 6, k = idx & 63;
        As[m * SA + k] *= invs[m];
    }
    __syncthreads();

    const int j0 = (tid & 15) << 2;
    const int m0 = (tid >> 4) << 2;
    float o[4][4];
    float4 b4 = *(const float4*)&bl[j0];
    #pragma unroll
    for (int mi = 0; mi < 4; ++mi) {
        o[mi][0] = b4.x; o[mi][1] = b4.y; o[mi][2] = b4.z; o[mi][3] = b4.w;
    }
    #pragma unroll 8
    for (int k = 0; k < D; ++k) {
        float4 wl = *(const float4*)&Wl[(k << 6) + j0];
        float4 wr = *(const float4*)&Wr[(k << 6) + j0];
        #pragma unroll
        for (int mi = 0; mi < 4; ++mi) {
            float a = As[(m0 + mi) * SA + k];
            float x = Xs[(m0 + mi) * SA + k];
            o[mi][0] += a * wl.x + x * wr.x;
            o[mi][1] += a * wl.y + x * wr.y;
            o[mi][2] += a * wl.z + x * wr.z;
            o[mi][3] += a * wl.w + x * wr.w;
        }
    }
    #pragma unroll
    for (int mi = 0; mi < 4; ++mi) {
        float4 r = make_float4(fmaxf(o[mi][0], 0.f), fmaxf(o[mi][1], 0.f),
                               fmaxf(o[mi][2], 0.f), fmaxf(o[mi][3], 0.f));
        *(float4*)&hout[(base + m0 + mi) * D + j0] = r;   // relu fused
    }
}

// ---------------- finish on compacted list (layer 1: ~4.3K nodes) ----------------

__global__ __launch_bounds__(256, 4) void sage_finish_sel(
    const float* __restrict__ hin, unsigned* __restrict__ aggb,
    const int* __restrict__ indeg, const int* __restrict__ list,
    const int* __restrict__ pcount, float* __restrict__ hout,
    const float* __restrict__ Wl, const float* __restrict__ bl,
    const float* __restrict__ Wr)
{
    __shared__ float As[TM * SA];
    __shared__ float Xs[TM * SA];
    __shared__ float invs[TM];
    __shared__ int   nid[TM];

    const int cntv = *pcount;
    const int base = blockIdx.x * TM;
    if (base >= cntv) return;

    const int tid = threadIdx.x;
    if (tid < TM) {
        int n = (base + tid < cntv) ? list[base + tid] : -1;
        nid[tid]  = n;
        invs[tid] = (n >= 0) ? 1.0f / (float)max(indeg[n], 1) : 0.f;
    }
    __syncthreads();
    for (int idx = tid; idx < TM * 32; idx += 256) {
        int m = idx >> 5, k2 = idx & 31;
        int n = nid[m];
        if (n >= 0) {
            unsigned v = aggb[(n << 5) + k2];
            As[m * SA + (k2 << 1)]     = __uint_as_float(v << 16) * invs[m];
            As[m * SA + (k2 << 1) + 1] = __uint_as_float(v & 0xffff0000u) * invs[m];
        } else {
            As[m * SA + (k2 << 1)]     = 0.f;
            As[m * SA + (k2 << 1) + 1] = 0.f;
        }
    }
    for (int idx = tid; idx < TM * D; idx += 256) {
        int m = idx >> 6, k = idx & 63;
        int n = nid[m];
        Xs[m * SA + k] = (n >= 0) ? hin[n * D + k] : 0.f;
    }
    __syncthreads();

    const int j0 = (tid & 15) << 2;
    const int m0 = (tid >> 4) << 2;
    float o[4][4];
    float4 b4 = *(const float4*)&bl[j0];
    #pragma unroll
    for (int mi = 0; mi < 4; ++mi) {
        o[mi][0] = b4.x; o[mi][1] = b4.y; o[mi][2] = b4.z; o[mi][3] = b4.w;
    }
    #pragma unroll 8
    for (int k = 0; k < D; ++k) {
        float4 wl = *(const float4*)&Wl[(k << 6) + j0];
        float4 wr = *(const float4*)&Wr[(k << 6) + j0];
        #pragma unroll
        for (int mi = 0; mi < 4; ++mi) {
            float a = As[(m0 + mi) * SA + k];
            float x = Xs[(m0 + mi) * SA + k];
            o[mi][0] += a * wl.x + x * wr.x;
            o[mi][1] += a * wl.y + x * wr.y;
            o[mi][2] += a * wl.z + x * wr.z;
            o[mi][3] += a * wl.w + x * wr.w;
        }
    }
    #pragma unroll
    for (int mi = 0; mi < 4; ++mi) {
        int n = nid[m0 + mi];
        if (n >= 0) {
            float4 r = make_float4(fmaxf(o[mi][0], 0.f), fmaxf(o[mi][1], 0.f),
                                   fmaxf(o[mi][2], 0.f), fmaxf(o[mi][3], 0.f));
            *(float4*)&hout[n * D + j0] = r;
        }
    }
}

// ---------------- final layer GEMM on the 256 selected nodes (exact f32 agg) --------

__global__ __launch_bounds__(256, 3) void final_gemm_sel(
    const float* __restrict__ hin, const float* __restrict__ agg,
    const int* __restrict__ indeg, const int* __restrict__ fidx,
    const float* __restrict__ Wl, const float* __restrict__ bl,
    const float* __restrict__ Wr, float* __restrict__ out)
{
    __shared__ float As[TM * SA];
    __shared__ float Xs[TM * SA];
    __shared__ int   nid[TM];
    __shared__ float invs[TM];

    const int tid  = threadIdx.x;
    const int base = blockIdx.x * TM;

    if (tid < TM) {
        int n = fidx[base + tid];
        nid[tid]  = n;
        invs[tid] = 1.0f / (float)max(indeg[n], 1);
    }
    __syncthreads();
    for (int idx = tid; idx < TM * D; idx += 256) {
        int m = idx >> 6, k = idx & 63;
        int n = nid[m];
        As[m * SA + k] = agg[n * D + k] * invs[m];
        Xs[m * SA + k] = hin[n * D + k];
    }
    __syncthreads();

    const int j0 = (tid & 15) << 2;
    const int m0 = (tid >> 4) << 2;
    float o[4][4];
    float4 b4 = *(const float4*)&bl[j0];
    #pragma unroll
    for (int mi = 0; mi < 4; ++mi) {
        o[mi][0] = b4.x; o[mi][1] = b4.y; o[mi][2] = b4.z; o[mi][3] = b4.w;
    }
    #pragma unroll 8
    for (int k = 0; k < D; ++k) {
        float4 wl = *(const float4*)&Wl[(k << 6) + j0];
        float4 wr = *(const float4*)&Wr[(k << 6) + j0];
        #pragma unroll
        for (int mi = 0; mi < 4; ++mi) {
            float a = As[(m0 + mi) * SA + k];
            float x = Xs[(m0 + mi) * SA + k];
            o[mi][0] += a * wl.x + x * wr.x;
            o[mi][1] += a * wl.y + x * wr.y;
            o[mi][2] += a * wl.z + x * wr.z;
            o[mi][3] += a * wl.w + x * wr.w;
        }
    }
    #pragma unroll
    for (int mi = 0; mi < 4; ++mi) {
        float4 r = make_float4(o[mi][0], o[mi][1], o[mi][2], o[mi][3]);
        *(float4*)&out[(base + m0 + mi) * D + j0] = r;
    }
}

// ---------------- launch ----------------

extern "C" void kernel_launch(void* const* d_in, const int* in_sizes, int n_in,
                              void* d_out, int out_size, void* d_ws, size_t ws_size,
                              hipStream_t stream)
{
    const float* x     = (const float*)d_in[0];
    const int*   ei    = (const int*)d_in[1];
    const int*   batch = (const int*)d_in[2];
    const float* Wl0 = (const float*)d_in[3];
    const float* bl0 = (const float*)d_in[4];
    const float* Wr0 = (const float*)d_in[5];
    const float* Wl1 = (const float*)d_in[6];
    const float* bl1 = (const float*)d_in[7];
    const float* Wr1 = (const float*)d_in[8];
    const float* Wl2 = (const float*)d_in[9];
    const float* bl2 = (const float*)d_in[10];
    const float* Wr2 = (const float*)d_in[11];
    float* out = (float*)d_out;

    const int* src = ei;             // edge_index[0]
    const int* dst = ei + N_EDGES;   // edge_index[1]

    char* ws = (char*)d_ws;
    size_t off = 0;
    auto alloc = [&](size_t bytes) -> void* {
        void* p = ws + off;
        off = (off + bytes + 255) & ~(size_t)255;
        return p;
    };
    int*      cur0  = (int*)alloc(NBLK * sizeof(int));
    int*      cur1  = (int*)alloc(NBLK * sizeof(int));
    int*      cur2  = (int*)alloc(NBLK * sizeof(int));
    int*      fidx  = (int*)alloc(NG * sizeof(int));
    int*      list1 = (int*)alloc(N_NODES * sizeof(int));
    int*      esp0  = (int*)alloc((size_t)NBLK * CAP0 * sizeof(int));
    int*      esp1  = (int*)alloc((size_t)NBLK * CAP1 * sizeof(int));
    int*      esp2  = (int*)alloc((size_t)NBLK * CAP2 * sizeof(int));
    unsigned* aggb  = (unsigned*)alloc((size_t)N_NODES * 32 * sizeof(unsigned)); // bf16x2
    float*    aggf  = (float*)alloc((size_t)N_NODES * D * sizeof(float));        // layer-2 exact
    float*    h1    = (float*)alloc((size_t)N_NODES * D * sizeof(float));
    float*    h2    = (float*)alloc((size_t)N_NODES * D * sizeof(float));
    unsigned* bms   = (unsigned*)alloc((size_t)3 * BMW * sizeof(unsigned));
    int*      indeg = (int*)alloc(N_NODES * sizeof(int));
    int*      n01   = (int*)alloc(64 * sizeof(int));
    unsigned* bm0 = bms;
    unsigned* bm1 = bms + BMW;
    unsigned* bm2 = bms + 2 * BMW;
    int* n1 = n01 + 1;
    (void)ws_size; (void)in_sizes; (void)n_in; (void)out_size;

    const int EB = (N_EDGES + 255) / 256;   // 5120

    init_ws<<<NBLK, 256, 0, stream>>>((float4*)aggb, bms, indeg, n01, cur0, cur1, cur2);
    ff_mark<<<NB, 256, 0, stream>>>(batch, fidx, bm2, bm1, aggf);
    mark_srcs_bm<<<EB, 256, 0, stream>>>(src, dst, bm2, bm1, (const unsigned*)nullptr);
    mark_srcs_bm<<<EB, 256, 0, stream>>>(src, dst, bm1, bm0, bm1);
    build<<<NB, 256, 0, stream>>>(src, dst, bm0, bm1, bm2, cur0, cur1, cur2,
                                  esp0, esp1, esp2, indeg, list1, n1);

    // layer 0: bf16 pk push + dense finish (all nodes, coalesced)
    sage_push_bf     <<<NBLK, 256, 0, stream>>>(x, cur0, esp0, aggb, CAP0);
    sage_finish_dense<<<NBLK, 256, 0, stream>>>(x, aggb, indeg, h1, Wl0, bl0, Wr0);
    // layer 1: bf16 pk push + list finish (~4.3K nodes)
    sage_push_bf     <<<NBLK, 256, 0, stream>>>(h1, cur1, esp1, aggb, CAP1);
    sage_finish_sel  <<<NBLK, 256, 0, stream>>>(h1, aggb, indeg, list1, n1,
                                                h2, Wl1, bl1, Wr1);
    // layer 2: exact f32 push into the 256 output rows + output GEMM
    sage_push_f32    <<<NBLK, 256, 0, stream>>>(h2, cur2, esp2, aggf, CAP2);
    final_gemm_sel   <<<NG / TM, 256, 0, stream>>>(h2, aggf, indeg, fidx, Wl2, bl2, Wr2, out);
}